// Round 3
// baseline (3469.448 us; speedup 1.0000x reference)
//
#include <hip/hip_runtime.h>
#include <math.h>

#define HD   128
#define HD2  256
#define LN_EPS 1e-5f
#define R1 16

static __device__ __forceinline__ float waveReduceSum(float v) {
#pragma unroll
  for (int off = 32; off >= 1; off >>= 1) v += __shfl_xor(v, off);
  return v;
}

static __device__ __forceinline__ float bf2f(unsigned short u) {
  union { unsigned int i; float f; } c; c.i = ((unsigned int)u) << 16; return c.f;
}

static __device__ __forceinline__ unsigned short f2bf(float f) {
  union { float f; unsigned int i; } c; c.f = f;
  unsigned int lsb = (c.i >> 16) & 1u;
  return (unsigned short)((c.i + 0x7fffu + lsb) >> 16);
}

__global__ void k_fill(float* __restrict__ p, float v, int n) {
  int i = blockIdx.x * blockDim.x + threadIdx.x;
  if (i < n) p[i] = v;
}

__global__ void k_count(const int* __restrict__ idx, float* __restrict__ deg, int e) {
  int i = blockIdx.x * blockDim.x + threadIdx.x;
  if (i < e) atomicAdd(&deg[idx[i]], 1.0f);
}

__global__ void k_rsqrt(float* __restrict__ d, int n) {
  int i = blockIdx.x * blockDim.x + threadIdx.x;
  if (i < n) d[i] = rsqrtf(d[i]);
}

__global__ void k_recip0(float* __restrict__ d, int n) {
  int i = blockIdx.x * blockDim.x + threadIdx.x;
  if (i < n) { float v = d[i]; d[i] = (v > 0.f) ? (1.f / v) : 0.f; }
}

// out[row] = src[row] * s[row]
__global__ void k_scale_rows(const float* __restrict__ src, const float* __restrict__ s,
                             float* __restrict__ out, int n) {
  int i = blockIdx.x * blockDim.x + threadIdx.x;
  if (i < n * (HD / 2)) {
    int row = i / (HD / 2);
    float2 v = reinterpret_cast<const float2*>(src)[i];
    float sc = s[row];
    v.x *= sc; v.y *= sc;
    reinterpret_cast<float2*>(out)[i] = v;
  }
}

// out[didx[i]] += srcbuf[sidx[i]] * (sscale ? sscale[sidx[i]] : 1), 64 lanes/edge
__global__ void k_scatter(const float* __restrict__ srcbuf, const float* __restrict__ sscale,
                          const int* __restrict__ sidx, const int* __restrict__ didx,
                          float* __restrict__ out, int e) {
  int t = blockIdx.x * blockDim.x + threadIdx.x;
  int edge = t >> 6;
  if (edge >= e) return;
  int l = t & 63;
  int s = sidx[edge], d = didx[edge];
  float sc = sscale ? sscale[s] : 1.0f;
  float2 v = reinterpret_cast<const float2*>(srcbuf)[(size_t)s * (HD / 2) + l];
  atomicAdd(&out[(size_t)d * HD + 2 * l],     v.x * sc);
  atomicAdd(&out[(size_t)d * HD + 2 * l + 1], v.y * sc);
}

// Fused: v = LN(relu((in*rs) @ W1 + b1))  (16 rows x 256 cols, LDS)
// then   h = v @ W2, val = h * (os ? os[row] : 1) -> outA (+ outB copy).
__global__ __launch_bounds__(256) void k_fused_gemm(
    const float* __restrict__ in, const float* __restrict__ rs,
    const float* __restrict__ W1, const float* __restrict__ b1,
    const float* __restrict__ g1, const float* __restrict__ be1,
    const float* __restrict__ W2, const float* __restrict__ os,
    float* __restrict__ outA, float* __restrict__ outB, int n) {
  __shared__ __align__(16) float smem[R1 * HD2];      // phase1: rb[16*128]; phase2: vb[16*256]
  __shared__ float red[2 * R1 * 4];
  __shared__ float stats[2 * R1];
  int tid = threadIdx.x;
  int row0 = blockIdx.x * R1;

  // load 16 rows x 128 (pre-scaled) into LDS
  for (int i = tid; i < R1 * HD; i += 256) {
    int r = i >> 7, c = i & 127;
    int row = row0 + r;
    float v = 0.f;
    if (row < n) v = in[(size_t)row * HD + c] * (rs ? rs[row] : 1.0f);
    smem[i] = v;
  }
  __syncthreads();

  // phase 1: col tid of W1 for all 16 rows
  float acc[R1];
#pragma unroll
  for (int r = 0; r < R1; ++r) acc[r] = 0.f;
  const float4* rb4 = reinterpret_cast<const float4*>(smem);
  for (int k4 = 0; k4 < HD / 4; ++k4) {
    int k = k4 * 4;
    float w0 = W1[(size_t)(k + 0) * HD2 + tid];
    float w1 = W1[(size_t)(k + 1) * HD2 + tid];
    float w2 = W1[(size_t)(k + 2) * HD2 + tid];
    float w3 = W1[(size_t)(k + 3) * HD2 + tid];
#pragma unroll
    for (int r = 0; r < R1; ++r) {
      float4 x = rb4[r * (HD / 4) + k4];
      acc[r] += x.x * w0 + x.y * w1 + x.z * w2 + x.w * w3;
    }
  }
  float bb = b1[tid], gg = g1[tid], bee = be1[tid];
#pragma unroll
  for (int r = 0; r < R1; ++r) acc[r] = fmaxf(acc[r] + bb, 0.f);

  // LN over 256 cols per row
  int wave = tid >> 6;
#pragma unroll
  for (int r = 0; r < R1; ++r) {
    float s = waveReduceSum(acc[r]);
    float q = waveReduceSum(acc[r] * acc[r]);
    if ((tid & 63) == 0) { red[r * 4 + wave] = s; red[R1 * 4 + r * 4 + wave] = q; }
  }
  __syncthreads();
  if (tid < R1) {
    float s = red[tid * 4] + red[tid * 4 + 1] + red[tid * 4 + 2] + red[tid * 4 + 3];
    float q = red[R1 * 4 + tid * 4] + red[R1 * 4 + tid * 4 + 1] +
              red[R1 * 4 + tid * 4 + 2] + red[R1 * 4 + tid * 4 + 3];
    float mean = s * (1.0f / HD2);
    float var = q * (1.0f / HD2) - mean * mean;
    stats[tid] = mean;
    stats[R1 + tid] = rsqrtf(var + LN_EPS);
  }
  __syncthreads();          // stats ready; all rb reads done -> safe to overwrite smem

  // write normalized 16x256 tile
#pragma unroll
  for (int r = 0; r < R1; ++r)
    smem[r * HD2 + tid] = (acc[r] - stats[r]) * stats[R1 + r] * gg + bee;
  __syncthreads();

  // phase 2: 2 groups x 128 threads; group g8 does rows [g8*8, g8*8+8), col j
  int g8 = tid >> 7, j = tid & 127;
  float acc2[8];
#pragma unroll
  for (int r = 0; r < 8; ++r) acc2[r] = 0.f;
  for (int k = 0; k < HD2; ++k) {
    float w = W2[(size_t)k * HD + j];
#pragma unroll
    for (int r = 0; r < 8; ++r) acc2[r] += smem[(g8 * 8 + r) * HD2 + k] * w;
  }
#pragma unroll
  for (int r = 0; r < 8; ++r) {
    int row = row0 + g8 * 8 + r;
    if (row < n) {
      float val = acc2[r] * (os ? os[row] : 1.0f);
      outA[(size_t)row * HD + j] = val;
      if (outB) outB[(size_t)row * HD + j] = val;
    }
  }
}

// out[row] = LN(relu(in[row]*s[row] + bias)); BF=1 -> bf16 output, else f32. In-place safe.
template <int BF>
__global__ __launch_bounds__(256) void k_final_ln(
    const float* __restrict__ in, const float* __restrict__ s,
    const float* __restrict__ bias, const float* __restrict__ g,
    const float* __restrict__ be, void* __restrict__ outp, int n) {
  int tid = threadIdx.x;
  int row = blockIdx.x * 4 + (tid >> 6);
  if (row >= n) return;
  int l = tid & 63;
  float sc = s[row];
  float2 v = reinterpret_cast<const float2*>(in)[(size_t)row * 64 + l];
  float2 bb = reinterpret_cast<const float2*>(bias)[l];
  float x0 = fmaxf(v.x * sc + bb.x, 0.f);
  float x1 = fmaxf(v.y * sc + bb.y, 0.f);
  float sum = waveReduceSum(x0 + x1);
  float sq  = waveReduceSum(x0 * x0 + x1 * x1);
  float mean = sum * (1.0f / HD);
  float var = sq * (1.0f / HD) - mean * mean;
  float rstd = rsqrtf(var + LN_EPS);
  float2 gg = reinterpret_cast<const float2*>(g)[l];
  float2 bbe = reinterpret_cast<const float2*>(be)[l];
  float o0 = (x0 - mean) * rstd * gg.x + bbe.x;
  float o1 = (x1 - mean) * rstd * gg.y + bbe.y;
  if (BF) {
    ushort2 o; o.x = f2bf(o0); o.y = f2bf(o1);
    reinterpret_cast<ushort2*>(outp)[(size_t)row * 64 + l] = o;
  } else {
    float2 o; o.x = o0; o.y = o1;
    reinterpret_cast<float2*>(outp)[(size_t)row * 64 + l] = o;
  }
}

// Per-node 3-key attention (Q=emb, K=V=[x1,x2,x3]) + LN. x1,x2 bf16; x3,out f32 (in-place ok).
__global__ __launch_bounds__(256) void k_fuse(
    const float* __restrict__ emb, const unsigned short* __restrict__ x1,
    const unsigned short* __restrict__ x2, const float* __restrict__ x3,
    const float* __restrict__ g, const float* __restrict__ be,
    float* __restrict__ out, int n) {
  int tid = threadIdx.x;
  int row = blockIdx.x * 4 + (tid >> 6);
  if (row >= n) return;
  int l = tid & 63;
  size_t base = (size_t)row * 64 + l;
  float2 q = reinterpret_cast<const float2*>(emb)[base];
  ushort2 u1 = reinterpret_cast<const ushort2*>(x1)[base];
  ushort2 u2 = reinterpret_cast<const ushort2*>(x2)[base];
  float2 a = make_float2(bf2f(u1.x), bf2f(u1.y));
  float2 b = make_float2(bf2f(u2.x), bf2f(u2.y));
  float2 c = reinterpret_cast<const float2*>(x3)[base];
  float d1 = waveReduceSum(q.x * a.x + q.y * a.y);
  float d2 = waveReduceSum(q.x * b.x + q.y * b.y);
  float d3 = waveReduceSum(q.x * c.x + q.y * c.y);
  const float is = 0.088388347648318447f; // 1/sqrt(128)
  float s1 = d1 * is, s2 = d2 * is, s3 = d3 * is;
  float m = fmaxf(s1, fmaxf(s2, s3));
  float p1 = expf(s1 - m), p2 = expf(s2 - m), p3 = expf(s3 - m);
  float den = 1.0f / (p1 + p2 + p3);
  p1 *= den; p2 *= den; p3 *= den;
  float ox = p1 * a.x + p2 * b.x + p3 * c.x;
  float oy = p1 * a.y + p2 * b.y + p3 * c.y;
  float sum = waveReduceSum(ox + oy);
  float sq  = waveReduceSum(ox * ox + oy * oy);
  float mean = sum * (1.0f / HD);
  float var = sq * (1.0f / HD) - mean * mean;
  float rstd = rsqrtf(var + LN_EPS);
  float2 gg = reinterpret_cast<const float2*>(g)[l];
  float2 bb = reinterpret_cast<const float2*>(be)[l];
  float2 o;
  o.x = (ox - mean) * rstd * gg.x + bb.x;
  o.y = (oy - mean) * rstd * gg.y + bb.y;
  reinterpret_cast<float2*>(out)[base] = o;
}

extern "C" void kernel_launch(void* const* d_in, const int* in_sizes, int n_in,
                              void* d_out, int out_size, void* d_ws, size_t ws_size,
                              hipStream_t stream) {
  (void)n_in; (void)out_size; (void)ws_size;
  const float* emb  = (const float*)d_in[0];
  const int* e_soc  = (const int*)d_in[1];
  const int* e_dif  = (const int*)d_in[2];
  const int* e_hyp  = (const int*)d_in[3];
  const float* fuse_g = (const float*)d_in[4];
  const float* fuse_b = (const float*)d_in[5];
  const int N  = in_sizes[0] / HD;
  const int E1 = in_sizes[1] / 2;
  const int E2 = in_sizes[2] / 2;
  const int E3 = in_sizes[3] / 2;
  float* dout = (float*)d_out;

  // workspace layout (155.2 MB @ N=100000): norms | A | B | X1(bf16) | X2(bf16)
  float* ws   = (float*)d_ws;
  float* dsoc = ws;
  float* ddif = dsoc + N;
  float* Dinv = ddif + N;
  float* Binv = Dinv + N;
  float* A    = Binv + N;
  float* B    = A + (size_t)N * HD;
  unsigned short* X1 = (unsigned short*)(B + (size_t)N * HD);
  unsigned short* X2 = X1 + (size_t)N * HD;

  int gN   = (N + 255) / 256;
  int gRow = (N + 3) / 4;
  int gG   = (N + R1 - 1) / R1;
  int gSR  = (N * (HD / 2) + 255) / 256;
  int gZ   = (N * HD + 255) / 256;

  // --- degree / norm factors ---
  k_fill<<<gN, 256, 0, stream>>>(dsoc, 1.0f, N);
  k_count<<<(E1 + 255) / 256, 256, 0, stream>>>(e_soc + E1, dsoc, E1);
  k_rsqrt<<<gN, 256, 0, stream>>>(dsoc, N);
  k_fill<<<gN, 256, 0, stream>>>(ddif, 1.0f, N);
  k_count<<<(E2 + 255) / 256, 256, 0, stream>>>(e_dif + E2, ddif, E2);
  k_rsqrt<<<gN, 256, 0, stream>>>(ddif, N);
  k_fill<<<gN, 256, 0, stream>>>(Dinv, 0.0f, N);
  k_count<<<(E3 + 255) / 256, 256, 0, stream>>>(e_hyp, Dinv, E3);
  k_recip0<<<gN, 256, 0, stream>>>(Dinv, N);
  k_fill<<<gN, 256, 0, stream>>>(Binv, 0.0f, N);
  k_count<<<(E3 + 255) / 256, 256, 0, stream>>>(e_hyp + E3, Binv, E3);
  k_recip0<<<gN, 256, 0, stream>>>(Binv, N);

  // --- two GCN paths (soc -> X1, dif -> X2); d_out = fp32 accumulation target ---
  for (int p = 0; p < 2; ++p) {
    const int* ei = (p == 0) ? e_soc : e_dif;
    const int  E  = (p == 0) ? E1 : E2;
    float* dinv   = (p == 0) ? dsoc : ddif;
    unsigned short* Xp = (p == 0) ? X1 : X2;
    const float* W1  = (const float*)d_in[6 + p * 8 + 0];
    const float* b1  = (const float*)d_in[6 + p * 8 + 1];
    const float* g1  = (const float*)d_in[6 + p * 8 + 2];
    const float* be1 = (const float*)d_in[6 + p * 8 + 3];
    const float* W2  = (const float*)d_in[6 + p * 8 + 4];
    const float* b2  = (const float*)d_in[6 + p * 8 + 5];
    const float* g2  = (const float*)d_in[6 + p * 8 + 6];
    const float* be2 = (const float*)d_in[6 + p * 8 + 7];
    int gSc = (E * 64 + 255) / 256;

    k_scale_rows<<<gSR, 256, 0, stream>>>(emb, dinv, A, N);                  // self-loop init
    k_scatter<<<gSc, 256, 0, stream>>>(emb, dinv, ei, ei + E, A, E);         // + dis[s]*x[s]
    k_fused_gemm<<<gG, 256, 0, stream>>>(A, dinv, W1, b1, g1, be1, W2, dinv,
                                         B, dout, N);                        // B=msgs, dout=self init
    k_scatter<<<gSc, 256, 0, stream>>>(B, nullptr, ei, ei + E, dout, E);
    k_final_ln<1><<<gRow, 256, 0, stream>>>(dout, dinv, b2, g2, be2, Xp, N);
  }

  // --- HGNN path (hyp -> X3 in d_out) ---
  {
    const float* W1  = (const float*)d_in[22 + 0];
    const float* b1  = (const float*)d_in[22 + 1];
    const float* g1  = (const float*)d_in[22 + 2];
    const float* be1 = (const float*)d_in[22 + 3];
    const float* W2  = (const float*)d_in[22 + 4];
    const float* b2  = (const float*)d_in[22 + 5];
    const float* g2  = (const float*)d_in[22 + 6];
    const float* be2 = (const float*)d_in[22 + 7];
    int gSc = (E3 * 64 + 255) / 256;

    k_fill<<<gZ, 256, 0, stream>>>(A, 0.0f, N * HD);
    k_scatter<<<gSc, 256, 0, stream>>>(emb, nullptr, e_hyp, e_hyp + E3, A, E3);   // node->he
    k_fill<<<gZ, 256, 0, stream>>>(B, 0.0f, N * HD);
    k_scatter<<<gSc, 256, 0, stream>>>(A, Binv, e_hyp + E3, e_hyp, B, E3);        // he->node *Binv
    k_fused_gemm<<<gG, 256, 0, stream>>>(B, Dinv, W1, b1, g1, be1, W2, nullptr,
                                         A, nullptr, N);                          // A = h2
    k_fill<<<gZ, 256, 0, stream>>>(B, 0.0f, N * HD);
    k_scatter<<<gSc, 256, 0, stream>>>(A, nullptr, e_hyp, e_hyp + E3, B, E3);     // node->he
    k_fill<<<gZ, 256, 0, stream>>>(dout, 0.0f, N * HD);
    k_scatter<<<gSc, 256, 0, stream>>>(B, Binv, e_hyp + E3, e_hyp, dout, E3);     // he->node *Binv
    k_final_ln<0><<<gRow, 256, 0, stream>>>(dout, Dinv, b2, g2, be2, dout, N);
  }

  // --- fusion attention + LN -> d_out (in-place over X3) ---
  k_fuse<<<gRow, 256, 0, stream>>>(emb, X1, X2, dout, fuse_g, fuse_b, dout, N);
}

// Round 4
// 1537.301 us; speedup vs baseline: 2.2568x; 2.2568x over previous
//
#include <hip/hip_runtime.h>
#include <math.h>

#define HD   128
#define HD2  256
#define LN_EPS 1e-5f
#define R1 16

typedef unsigned short us8 __attribute__((ext_vector_type(8)));

static __device__ __forceinline__ float waveReduceSum(float v) {
#pragma unroll
  for (int off = 32; off >= 1; off >>= 1) v += __shfl_xor(v, off);
  return v;
}

static __device__ __forceinline__ float bf2f(unsigned short u) {
  union { unsigned int i; float f; } c; c.i = ((unsigned int)u) << 16; return c.f;
}

static __device__ __forceinline__ unsigned short f2bf(float f) {
  union { float f; unsigned int i; } c; c.f = f;
  unsigned int lsb = (c.i >> 16) & 1u;
  return (unsigned short)((c.i + 0x7fffu + lsb) >> 16);
}

// ---------------- CSR build ----------------
__global__ void k_izero(int* __restrict__ p, int n) {
  int i = blockIdx.x * blockDim.x + threadIdx.x;
  if (i < n) p[i] = 0;
}

__global__ void k_icount(const int* __restrict__ idx, int* __restrict__ deg, int e) {
  int i = blockIdx.x * blockDim.x + threadIdx.x;
  if (i < e) atomicAdd(&deg[idx[i]], 1);
}

__global__ void k_norms(const int* __restrict__ cs, const int* __restrict__ cd,
                        const int* __restrict__ chn, const int* __restrict__ che,
                        float* __restrict__ dsoc, float* __restrict__ ddif,
                        float* __restrict__ Dinv, float* __restrict__ Binv, int n) {
  int i = blockIdx.x * blockDim.x + threadIdx.x;
  if (i >= n) return;
  dsoc[i] = rsqrtf((float)(cs[i] + 1));
  ddif[i] = rsqrtf((float)(cd[i] + 1));
  int dn = chn[i]; Dinv[i] = dn > 0 ? 1.0f / (float)dn : 0.0f;
  int bh = che[i]; Binv[i] = bh > 0 ? 1.0f / (float)bh : 0.0f;
}

__global__ __launch_bounds__(256) void k_bsum(const int* __restrict__ deg,
                                              int* __restrict__ bsum, int n) {
  __shared__ int sh[256];
  int t = threadIdx.x;
  int i = blockIdx.x * 256 + t;
  sh[t] = (i < n) ? deg[i] : 0;
  __syncthreads();
  for (int d = 128; d > 0; d >>= 1) { if (t < d) sh[t] += sh[t + d]; __syncthreads(); }
  if (t == 0) bsum[blockIdx.x] = sh[0];
}

__global__ __launch_bounds__(1024) void k_scanblk(const int* __restrict__ bsum,
                                                  int* __restrict__ bbase, int nb) {
  __shared__ int sh[1024];
  int t = threadIdx.x;
  int v = (t < nb) ? bsum[t] : 0;
  sh[t] = v;
  __syncthreads();
  for (int d = 1; d < 1024; d <<= 1) {
    int x = (t >= d) ? sh[t - d] : 0;
    __syncthreads();
    sh[t] += x;
    __syncthreads();
  }
  if (t < nb) bbase[t] = sh[t] - v;   // exclusive
}

__global__ __launch_bounds__(256) void k_fillof(const int* __restrict__ deg,
                                                const int* __restrict__ bbase,
                                                int* __restrict__ off, int* __restrict__ cur,
                                                int n) {
  __shared__ int sh[256];
  int t = threadIdx.x;
  int i = blockIdx.x * 256 + t;
  int v = (i < n) ? deg[i] : 0;
  sh[t] = v;
  __syncthreads();
  for (int d = 1; d < 256; d <<= 1) {
    int x = (t >= d) ? sh[t - d] : 0;
    __syncthreads();
    sh[t] += x;
    __syncthreads();
  }
  if (i < n) { int e = bbase[blockIdx.x] + sh[t] - v; off[i] = e; cur[i] = e; }
}

__global__ void k_fillcol(const int* __restrict__ sidx, const int* __restrict__ didx,
                          int* __restrict__ cur, int* __restrict__ colv, int e) {
  int i = blockIdx.x * blockDim.x + threadIdx.x;
  if (i < e) {
    int d = didx[i];
    int slot = atomicAdd(&cur[d], 1);
    colv[slot] = sidx[i];
  }
}

// fp32 -> bf16 bulk convert (vectorized)
__global__ void k_cvt(const float* __restrict__ in, unsigned short* __restrict__ out, int n4) {
  int i = blockIdx.x * blockDim.x + threadIdx.x;
  if (i < n4) {
    float4 v = reinterpret_cast<const float4*>(in)[i];
    ushort4 o;
    o.x = f2bf(v.x); o.y = f2bf(v.y); o.z = f2bf(v.z); o.w = f2bf(v.w);
    reinterpret_cast<ushort4*>(out)[i] = o;
  }
}

// ---------------- gather aggregation (one wave per dst row, bf16 in/out) ----------------
// out[d] = dscale[d] * ( selfterm + sum_{j in CSR[d]} sscale[col_j] * src[col_j] )
// selfmode: 0 none, 1 unit (src[d]), 2 selfs[d]*src[d]
__global__ __launch_bounds__(256) void k_gather(
    const unsigned short* __restrict__ src, const float* __restrict__ sscale,
    const float* __restrict__ selfs, int selfmode, const float* __restrict__ dscale,
    const int* __restrict__ off, const int* __restrict__ endp,
    const int* __restrict__ colv, unsigned short* __restrict__ out, int n) {
  int tid = threadIdx.x;
  int row = blockIdx.x * 4 + (tid >> 6);
  if (row >= n) return;
  int l = tid & 63;
  const ushort2* s2 = reinterpret_cast<const ushort2*>(src);
  float ax = 0.f, ay = 0.f;
  if (selfmode) {
    float ss = (selfmode == 2) ? selfs[row] : 1.0f;
    ushort2 u = s2[(size_t)row * 64 + l];
    ax = bf2f(u.x) * ss; ay = bf2f(u.y) * ss;
  }
  int j0 = off[row], j1 = endp[row];
  if (sscale) {
    for (int j = j0; j < j1; ++j) {
      int s = colv[j];
      float sc = sscale[s];
      ushort2 u = s2[(size_t)s * 64 + l];
      ax += bf2f(u.x) * sc; ay += bf2f(u.y) * sc;
    }
  } else {
    for (int j = j0; j < j1; ++j) {
      int s = colv[j];
      ushort2 u = s2[(size_t)s * 64 + l];
      ax += bf2f(u.x); ay += bf2f(u.y);
    }
  }
  if (dscale) { float dsc = dscale[row]; ax *= dsc; ay *= dsc; }
  ushort2 o; o.x = f2bf(ax); o.y = f2bf(ay);
  reinterpret_cast<ushort2*>(out)[(size_t)row * 64 + l] = o;
}

// ---------------- fused GEMM1 + bias + relu + LN + GEMM2 ----------------
// in: bf16 [n][128] (row-scaled by rs); T = LN(relu((in*rs)@W1 + b1)) in LDS;
// out = bf16( (T@W2) * (os ? os[row] : 1) )
__global__ __launch_bounds__(256) void k_fused_gemm(
    const unsigned short* __restrict__ in, const float* __restrict__ rs,
    const float* __restrict__ W1, const float* __restrict__ b1,
    const float* __restrict__ g1, const float* __restrict__ be1,
    const float* __restrict__ W2, const float* __restrict__ os,
    unsigned short* __restrict__ out, int n) {
  __shared__ __align__(16) float smem[R1 * HD2];  // phase1: rb 16x128; phase2: vb 16x256
  __shared__ float red[2 * R1 * 2];               // [sum|sq][row][wavehalf]
  __shared__ float stats[2 * R1];
  int tid = threadIdx.x;
  int row0 = blockIdx.x * R1;

  { // stage-in: 16 rows x 128 bf16 -> fp32*rs
    int r = tid >> 4, c0 = (tid & 15) * 8;
    int row = row0 + r;
    float vv[8];
    if (row < n) {
      us8 u = *reinterpret_cast<const us8*>(&in[(size_t)row * HD + c0]);
      float rv = rs ? rs[row] : 1.0f;
#pragma unroll
      for (int j = 0; j < 8; ++j) vv[j] = bf2f((unsigned short)u[j]) * rv;
    } else {
#pragma unroll
      for (int j = 0; j < 8; ++j) vv[j] = 0.f;
    }
#pragma unroll
    for (int j = 0; j < 8; ++j) smem[r * HD + c0 + j] = vv[j];
  }
  __syncthreads();

  // phase 1: 2 cols (jc, jc+128) x 8 rows (rg*8..) per thread
  int jc = tid & 127, rg = tid >> 7;
  float acc[8][2];
#pragma unroll
  for (int r = 0; r < 8; ++r) { acc[r][0] = 0.f; acc[r][1] = 0.f; }
  const float4* rb4 = reinterpret_cast<const float4*>(smem);
  for (int k4 = 0; k4 < HD / 4; ++k4) {
    int k = k4 * 4;
    float wa0 = W1[(size_t)(k + 0) * HD2 + jc], wb0 = W1[(size_t)(k + 0) * HD2 + jc + 128];
    float wa1 = W1[(size_t)(k + 1) * HD2 + jc], wb1 = W1[(size_t)(k + 1) * HD2 + jc + 128];
    float wa2 = W1[(size_t)(k + 2) * HD2 + jc], wb2 = W1[(size_t)(k + 2) * HD2 + jc + 128];
    float wa3 = W1[(size_t)(k + 3) * HD2 + jc], wb3 = W1[(size_t)(k + 3) * HD2 + jc + 128];
#pragma unroll
    for (int r = 0; r < 8; ++r) {
      float4 x = rb4[(rg * 8 + r) * (HD / 4) + k4];
      acc[r][0] += x.x * wa0 + x.y * wa1 + x.z * wa2 + x.w * wa3;
      acc[r][1] += x.x * wb0 + x.y * wb1 + x.z * wb2 + x.w * wb3;
    }
  }
  float bb0 = b1[jc], bb1 = b1[jc + 128];
#pragma unroll
  for (int r = 0; r < 8; ++r) {
    acc[r][0] = fmaxf(acc[r][0] + bb0, 0.f);
    acc[r][1] = fmaxf(acc[r][1] + bb1, 0.f);
  }

  // LN over 256 cols per row
  int wh = (tid >> 6) & 1;  // which wave-half of this row-group
#pragma unroll
  for (int r = 0; r < 8; ++r) {
    int R = rg * 8 + r;
    float s = waveReduceSum(acc[r][0] + acc[r][1]);
    float q = waveReduceSum(acc[r][0] * acc[r][0] + acc[r][1] * acc[r][1]);
    if ((tid & 63) == 0) { red[R * 2 + wh] = s; red[2 * R1 + R * 2 + wh] = q; }
  }
  __syncthreads();
  if (tid < R1) {
    float s = red[tid * 2] + red[tid * 2 + 1];
    float q = red[2 * R1 + tid * 2] + red[2 * R1 + tid * 2 + 1];
    float mean = s * (1.0f / HD2);
    float var = q * (1.0f / HD2) - mean * mean;
    stats[tid] = mean;
    stats[R1 + tid] = rsqrtf(var + LN_EPS);
  }
  __syncthreads();
  float gg0 = g1[jc], gg1 = g1[jc + 128], ee0 = be1[jc], ee1 = be1[jc + 128];
#pragma unroll
  for (int r = 0; r < 8; ++r) {
    int R = rg * 8 + r;
    smem[R * HD2 + jc]       = (acc[r][0] - stats[R]) * stats[R1 + R] * gg0 + ee0;
    smem[R * HD2 + jc + 128] = (acc[r][1] - stats[R]) * stats[R1 + R] * gg1 + ee1;
  }
  __syncthreads();

  // phase 2: wave w2r does rows w2r*4..+3; cols jc2, jc2+64
  int w2r = tid >> 6, jc2 = tid & 63;
  float a2[4][2];
#pragma unroll
  for (int r = 0; r < 4; ++r) { a2[r][0] = 0.f; a2[r][1] = 0.f; }
  const float4* vb4 = reinterpret_cast<const float4*>(smem);
  for (int k4 = 0; k4 < HD2 / 4; ++k4) {
    int k = k4 * 4;
    float wa0 = W2[(size_t)(k + 0) * HD + jc2], wb0 = W2[(size_t)(k + 0) * HD + jc2 + 64];
    float wa1 = W2[(size_t)(k + 1) * HD + jc2], wb1 = W2[(size_t)(k + 1) * HD + jc2 + 64];
    float wa2 = W2[(size_t)(k + 2) * HD + jc2], wb2 = W2[(size_t)(k + 2) * HD + jc2 + 64];
    float wa3 = W2[(size_t)(k + 3) * HD + jc2], wb3 = W2[(size_t)(k + 3) * HD + jc2 + 64];
#pragma unroll
    for (int r = 0; r < 4; ++r) {
      float4 x = vb4[(w2r * 4 + r) * (HD2 / 4) + k4];
      a2[r][0] += x.x * wa0 + x.y * wa1 + x.z * wa2 + x.w * wa3;
      a2[r][1] += x.x * wb0 + x.y * wb1 + x.z * wb2 + x.w * wb3;
    }
  }
#pragma unroll
  for (int r = 0; r < 4; ++r) {
    int row = row0 + w2r * 4 + r;
    if (row < n) {
      float sc = os ? os[row] : 1.0f;
      out[(size_t)row * HD + jc2]      = f2bf(a2[r][0] * sc);
      out[(size_t)row * HD + jc2 + 64] = f2bf(a2[r][1] * sc);
    }
  }
}

// out[row] = LN(relu(in[row]*s[row] + bias)); in bf16. OUTBF=1 -> bf16 out, else f32.
template <int OUTBF>
__global__ __launch_bounds__(256) void k_final_ln(
    const unsigned short* __restrict__ in, const float* __restrict__ s,
    const float* __restrict__ bias, const float* __restrict__ g,
    const float* __restrict__ be, void* __restrict__ outp, int n) {
  int tid = threadIdx.x;
  int row = blockIdx.x * 4 + (tid >> 6);
  if (row >= n) return;
  int l = tid & 63;
  float sc = s[row];
  ushort2 u = reinterpret_cast<const ushort2*>(in)[(size_t)row * 64 + l];
  float2 bb = reinterpret_cast<const float2*>(bias)[l];
  float x0 = fmaxf(bf2f(u.x) * sc + bb.x, 0.f);
  float x1 = fmaxf(bf2f(u.y) * sc + bb.y, 0.f);
  float sum = waveReduceSum(x0 + x1);
  float sq  = waveReduceSum(x0 * x0 + x1 * x1);
  float mean = sum * (1.0f / HD);
  float var = sq * (1.0f / HD) - mean * mean;
  float rstd = rsqrtf(var + LN_EPS);
  float2 gg = reinterpret_cast<const float2*>(g)[l];
  float2 bbe = reinterpret_cast<const float2*>(be)[l];
  float o0 = (x0 - mean) * rstd * gg.x + bbe.x;
  float o1 = (x1 - mean) * rstd * gg.y + bbe.y;
  if (OUTBF) {
    ushort2 o; o.x = f2bf(o0); o.y = f2bf(o1);
    reinterpret_cast<ushort2*>(outp)[(size_t)row * 64 + l] = o;
  } else {
    float2 o; o.x = o0; o.y = o1;
    reinterpret_cast<float2*>(outp)[(size_t)row * 64 + l] = o;
  }
}

// Per-node 3-key attention + LN. x1,x2 bf16; x3 f32 (in-place with out ok).
__global__ __launch_bounds__(256) void k_fuse(
    const float* __restrict__ emb, const unsigned short* __restrict__ x1,
    const unsigned short* __restrict__ x2, const float* __restrict__ x3,
    const float* __restrict__ g, const float* __restrict__ be,
    float* __restrict__ out, int n) {
  int tid = threadIdx.x;
  int row = blockIdx.x * 4 + (tid >> 6);
  if (row >= n) return;
  int l = tid & 63;
  size_t base = (size_t)row * 64 + l;
  float2 q = reinterpret_cast<const float2*>(emb)[base];
  ushort2 u1 = reinterpret_cast<const ushort2*>(x1)[base];
  ushort2 u2 = reinterpret_cast<const ushort2*>(x2)[base];
  float2 a = make_float2(bf2f(u1.x), bf2f(u1.y));
  float2 b = make_float2(bf2f(u2.x), bf2f(u2.y));
  float2 c = reinterpret_cast<const float2*>(x3)[base];
  float d1 = waveReduceSum(q.x * a.x + q.y * a.y);
  float d2 = waveReduceSum(q.x * b.x + q.y * b.y);
  float d3 = waveReduceSum(q.x * c.x + q.y * c.y);
  const float is = 0.088388347648318447f; // 1/sqrt(128)
  float s1 = d1 * is, s2 = d2 * is, s3 = d3 * is;
  float m = fmaxf(s1, fmaxf(s2, s3));
  float p1 = expf(s1 - m), p2 = expf(s2 - m), p3 = expf(s3 - m);
  float den = 1.0f / (p1 + p2 + p3);
  p1 *= den; p2 *= den; p3 *= den;
  float ox = p1 * a.x + p2 * b.x + p3 * c.x;
  float oy = p1 * a.y + p2 * b.y + p3 * c.y;
  float sum = waveReduceSum(ox + oy);
  float sq  = waveReduceSum(ox * ox + oy * oy);
  float mean = sum * (1.0f / HD);
  float var = sq * (1.0f / HD) - mean * mean;
  float rstd = rsqrtf(var + LN_EPS);
  float2 gg = reinterpret_cast<const float2*>(g)[l];
  float2 bb = reinterpret_cast<const float2*>(be)[l];
  float2 o;
  o.x = (ox - mean) * rstd * gg.x + bb.x;
  o.y = (oy - mean) * rstd * gg.y + bb.y;
  reinterpret_cast<float2*>(out)[base] = o;
}

extern "C" void kernel_launch(void* const* d_in, const int* in_sizes, int n_in,
                              void* d_out, int out_size, void* d_ws, size_t ws_size,
                              hipStream_t stream) {
  (void)n_in; (void)out_size; (void)ws_size;
  const float* emb  = (const float*)d_in[0];
  const int* e_soc  = (const int*)d_in[1];
  const int* e_dif  = (const int*)d_in[2];
  const int* e_hyp  = (const int*)d_in[3];
  const float* fuse_g = (const float*)d_in[4];
  const float* fuse_b = (const float*)d_in[5];
  const int N  = in_sizes[0] / HD;
  const int E1 = in_sizes[1] / 2;
  const int E2 = in_sizes[2] / 2;
  const int E3 = in_sizes[3] / 2;
  float* dout = (float*)d_out;

  // ---- workspace carve-up (~140 MB) ----
  char* wsb = (char*)d_ws;
  size_t o = 0;
  auto alloc = [&](size_t bytes) { void* p = wsb + o; o = (o + bytes + 15) & ~(size_t)15; return p; };
  int* deg_soc = (int*)alloc((size_t)4 * N * 4);
  int* deg_dif = deg_soc + N;
  int* deg_hn  = deg_soc + 2 * (size_t)N;
  int* deg_he  = deg_soc + 3 * (size_t)N;
  int* cur_soc = (int*)alloc((size_t)4 * N * 4);
  int* cur_dif = cur_soc + N;
  int* cur_hn  = cur_soc + 2 * (size_t)N;
  int* cur_he  = cur_soc + 3 * (size_t)N;
  int* off_soc = (int*)alloc((size_t)4 * N * 4);
  int* off_dif = off_soc + N;
  int* off_hn  = off_soc + 2 * (size_t)N;
  int* off_he  = off_soc + 3 * (size_t)N;
  int* bsum4  = (int*)alloc(4 * 1024 * 4);
  int* bbase4 = (int*)alloc(4 * 1024 * 4);
  int* col_soc = (int*)alloc((size_t)E1 * 4);
  int* col_dif = (int*)alloc((size_t)E2 * 4);
  int* col_hn  = (int*)alloc((size_t)E3 * 4);
  int* col_he  = (int*)alloc((size_t)E3 * 4);
  float* dsoc = (float*)alloc((size_t)N * 4);
  float* ddif = (float*)alloc((size_t)N * 4);
  float* Dinv = (float*)alloc((size_t)N * 4);
  float* Binv = (float*)alloc((size_t)N * 4);
  unsigned short* emb_bf = (unsigned short*)alloc((size_t)N * HD * 2);
  unsigned short* A_bf   = (unsigned short*)alloc((size_t)N * HD * 2);
  unsigned short* B_bf   = (unsigned short*)alloc((size_t)N * HD * 2);
  unsigned short* X1     = (unsigned short*)alloc((size_t)N * HD * 2);
  unsigned short* X2     = (unsigned short*)alloc((size_t)N * HD * 2);

  const int NB = (N + 255) / 256;
  int gN   = (N + 255) / 256;
  int gRow = (N + 3) / 4;
  int gG   = (N + R1 - 1) / R1;

  // ---- degrees ----
  k_izero<<<(4 * N + 255) / 256, 256, 0, stream>>>(deg_soc, 4 * N);
  k_icount<<<(E1 + 255) / 256, 256, 0, stream>>>(e_soc + E1, deg_soc, E1);
  k_icount<<<(E2 + 255) / 256, 256, 0, stream>>>(e_dif + E2, deg_dif, E2);
  k_icount<<<(E3 + 255) / 256, 256, 0, stream>>>(e_hyp,      deg_hn,  E3);
  k_icount<<<(E3 + 255) / 256, 256, 0, stream>>>(e_hyp + E3, deg_he,  E3);
  k_norms<<<gN, 256, 0, stream>>>(deg_soc, deg_dif, deg_hn, deg_he, dsoc, ddif, Dinv, Binv, N);

  // ---- CSR offsets + columns (4 graphs) ----
  const int* degs[4] = {deg_soc, deg_dif, deg_hn, deg_he};
  int* curs[4] = {cur_soc, cur_dif, cur_hn, cur_he};
  int* offs[4] = {off_soc, off_dif, off_hn, off_he};
  for (int g = 0; g < 4; ++g) {
    k_bsum<<<NB, 256, 0, stream>>>(degs[g], bsum4 + g * 1024, N);
    k_scanblk<<<1, 1024, 0, stream>>>(bsum4 + g * 1024, bbase4 + g * 1024, NB);
    k_fillof<<<NB, 256, 0, stream>>>(degs[g], bbase4 + g * 1024, offs[g], curs[g], N);
  }
  k_fillcol<<<(E1 + 255) / 256, 256, 0, stream>>>(e_soc,      e_soc + E1, cur_soc, col_soc, E1);
  k_fillcol<<<(E2 + 255) / 256, 256, 0, stream>>>(e_dif,      e_dif + E2, cur_dif, col_dif, E2);
  k_fillcol<<<(E3 + 255) / 256, 256, 0, stream>>>(e_hyp + E3, e_hyp,      cur_hn,  col_hn,  E3); // node -> list of he
  k_fillcol<<<(E3 + 255) / 256, 256, 0, stream>>>(e_hyp,      e_hyp + E3, cur_he,  col_he,  E3); // he -> list of node

  // ---- emb -> bf16 once ----
  k_cvt<<<(N * HD / 4 + 255) / 256, 256, 0, stream>>>(emb, emb_bf, N * HD / 4);

  // ---- two GCN paths (soc -> X1, dif -> X2) ----
  for (int p = 0; p < 2; ++p) {
    float* dinv = (p == 0) ? dsoc : ddif;
    const int* off = offs[p];
    const int* end = curs[p];     // cur == end pointers after fill
    const int* col = (p == 0) ? col_soc : col_dif;
    unsigned short* Xp = (p == 0) ? X1 : X2;
    const float* W1  = (const float*)d_in[6 + p * 8 + 0];
    const float* b1  = (const float*)d_in[6 + p * 8 + 1];
    const float* g1  = (const float*)d_in[6 + p * 8 + 2];
    const float* be1 = (const float*)d_in[6 + p * 8 + 3];
    const float* W2  = (const float*)d_in[6 + p * 8 + 4];
    const float* b2  = (const float*)d_in[6 + p * 8 + 5];
    const float* g2  = (const float*)d_in[6 + p * 8 + 6];
    const float* be2 = (const float*)d_in[6 + p * 8 + 7];

    k_gather<<<gRow, 256, 0, stream>>>(emb_bf, dinv, dinv, 2, nullptr, off, end, col, A_bf, N);
    k_fused_gemm<<<gG, 256, 0, stream>>>(A_bf, dinv, W1, b1, g1, be1, W2, dinv, B_bf, N);
    k_gather<<<gRow, 256, 0, stream>>>(B_bf, nullptr, nullptr, 1, nullptr, off, end, col, A_bf, N);
    k_final_ln<1><<<gRow, 256, 0, stream>>>(A_bf, dinv, b2, g2, be2, Xp, N);
  }

  // ---- HGNN path (hyp -> dout) ----
  {
    const float* W1  = (const float*)d_in[22 + 0];
    const float* b1  = (const float*)d_in[22 + 1];
    const float* g1  = (const float*)d_in[22 + 2];
    const float* be1 = (const float*)d_in[22 + 3];
    const float* W2  = (const float*)d_in[22 + 4];
    const float* b2  = (const float*)d_in[22 + 5];
    const float* g2  = (const float*)d_in[22 + 6];
    const float* be2 = (const float*)d_in[22 + 7];

    // He = Binv * sum_{node in he} emb
    k_gather<<<gRow, 256, 0, stream>>>(emb_bf, nullptr, nullptr, 0, Binv, off_he, cur_he, col_he, A_bf, N);
    // Bv[node] = sum_{he ∋ node} He
    k_gather<<<gRow, 256, 0, stream>>>(A_bf, nullptr, nullptr, 0, nullptr, off_hn, cur_hn, col_hn, B_bf, N);
    // A2 = LN(relu((Dinv*Bv)@W1+b1)) @ W2
    k_fused_gemm<<<gG, 256, 0, stream>>>(B_bf, Dinv, W1, b1, g1, be1, W2, nullptr, A_bf, N);
    // He2 = Binv * sum_{node} A2 ; O = sum_{he} He2
    k_gather<<<gRow, 256, 0, stream>>>(A_bf, nullptr, nullptr, 0, Binv, off_he, cur_he, col_he, B_bf, N);
    k_gather<<<gRow, 256, 0, stream>>>(B_bf, nullptr, nullptr, 0, nullptr, off_hn, cur_hn, col_hn, A_bf, N);
    k_final_ln<0><<<gRow, 256, 0, stream>>>(A_bf, Dinv, b2, g2, be2, dout, N);
  }

  // ---- fusion attention + LN -> d_out (in-place over X3) ----
  k_fuse<<<gRow, 256, 0, stream>>>(emb, X1, X2, dout, fuse_g, fuse_b, dout, N);
}

// Round 5
// 918.753 us; speedup vs baseline: 3.7763x; 1.6732x over previous
//
#include <hip/hip_runtime.h>
#include <math.h>

#define HD   128
#define HD2  256
#define LN_EPS 1e-5f
#define BM 32
#define PX 136   // X LDS pitch in bf16 elems (128 + 8 pad)
#define PT 264   // T LDS pitch in bf16 elems (256 + 8 pad)

typedef __attribute__((ext_vector_type(8))) short s8v;    // 8 x bf16 (4 VGPR)
typedef __attribute__((ext_vector_type(4))) float f4v;    // MFMA acc

static __device__ __forceinline__ float waveReduceSum(float v) {
#pragma unroll
  for (int off = 32; off >= 1; off >>= 1) v += __shfl_xor(v, off);
  return v;
}

static __device__ __forceinline__ float bf2f(unsigned short u) {
  union { unsigned int i; float f; } c; c.i = ((unsigned int)u) << 16; return c.f;
}

static __device__ __forceinline__ unsigned short f2bf(float f) {
  union { float f; unsigned int i; } c; c.f = f;
  unsigned int lsb = (c.i >> 16) & 1u;
  return (unsigned short)((c.i + 0x7fffu + lsb) >> 16);
}

// ---------------- CSR build ----------------
__global__ void k_izero(int* __restrict__ p, int n) {
  int i = blockIdx.x * blockDim.x + threadIdx.x;
  if (i < n) p[i] = 0;
}

__global__ void k_icount(const int* __restrict__ idx, int* __restrict__ deg, int e) {
  int i = blockIdx.x * blockDim.x + threadIdx.x;
  if (i < e) atomicAdd(&deg[idx[i]], 1);
}

__global__ void k_norms(const int* __restrict__ cs, const int* __restrict__ cd,
                        const int* __restrict__ chn, const int* __restrict__ che,
                        float* __restrict__ dsoc, float* __restrict__ ddif,
                        float* __restrict__ Dinv, float* __restrict__ Binv, int n) {
  int i = blockIdx.x * blockDim.x + threadIdx.x;
  if (i >= n) return;
  dsoc[i] = rsqrtf((float)(cs[i] + 1));
  ddif[i] = rsqrtf((float)(cd[i] + 1));
  int dn = chn[i]; Dinv[i] = dn > 0 ? 1.0f / (float)dn : 0.0f;
  int bh = che[i]; Binv[i] = bh > 0 ? 1.0f / (float)bh : 0.0f;
}

__global__ __launch_bounds__(256) void k_bsum(const int* __restrict__ deg,
                                              int* __restrict__ bsum, int n) {
  __shared__ int sh[256];
  int t = threadIdx.x;
  int i = blockIdx.x * 256 + t;
  sh[t] = (i < n) ? deg[i] : 0;
  __syncthreads();
  for (int d = 128; d > 0; d >>= 1) { if (t < d) sh[t] += sh[t + d]; __syncthreads(); }
  if (t == 0) bsum[blockIdx.x] = sh[0];
}

__global__ __launch_bounds__(1024) void k_scanblk(const int* __restrict__ bsum,
                                                  int* __restrict__ bbase, int nb) {
  __shared__ int sh[1024];
  int t = threadIdx.x;
  int v = (t < nb) ? bsum[t] : 0;
  sh[t] = v;
  __syncthreads();
  for (int d = 1; d < 1024; d <<= 1) {
    int x = (t >= d) ? sh[t - d] : 0;
    __syncthreads();
    sh[t] += x;
    __syncthreads();
  }
  if (t < nb) bbase[t] = sh[t] - v;   // exclusive
}

__global__ __launch_bounds__(256) void k_fillof(const int* __restrict__ deg,
                                                const int* __restrict__ bbase,
                                                int* __restrict__ off, int* __restrict__ cur,
                                                int n) {
  __shared__ int sh[256];
  int t = threadIdx.x;
  int i = blockIdx.x * 256 + t;
  int v = (i < n) ? deg[i] : 0;
  sh[t] = v;
  __syncthreads();
  for (int d = 1; d < 256; d <<= 1) {
    int x = (t >= d) ? sh[t - d] : 0;
    __syncthreads();
    sh[t] += x;
    __syncthreads();
  }
  if (i < n) { int e = bbase[blockIdx.x] + sh[t] - v; off[i] = e; cur[i] = e; }
}

__global__ void k_fillcol(const int* __restrict__ sidx, const int* __restrict__ didx,
                          int* __restrict__ cur, int* __restrict__ colv, int e) {
  int i = blockIdx.x * blockDim.x + threadIdx.x;
  if (i < e) {
    int d = didx[i];
    int slot = atomicAdd(&cur[d], 1);
    colv[slot] = sidx[i];
  }
}

// fp32 -> bf16 bulk convert (vectorized)
__global__ void k_cvt(const float* __restrict__ in, unsigned short* __restrict__ out, int n4) {
  int i = blockIdx.x * blockDim.x + threadIdx.x;
  if (i < n4) {
    float4 v = reinterpret_cast<const float4*>(in)[i];
    ushort4 o;
    o.x = f2bf(v.x); o.y = f2bf(v.y); o.z = f2bf(v.z); o.w = f2bf(v.w);
    reinterpret_cast<ushort4*>(out)[i] = o;
  }
}

// W [K][NC] fp32 -> fragment-ordered bf16: Wf[((ct*KT+kt)*64+l)*8+b] = W[kt*32+(l>>4)*8+b][ct*16+(l&15)]
__global__ void k_wfrag(const float* __restrict__ W, unsigned short* __restrict__ Wf,
                        int KT, int NC, int total) {
  int t = blockIdx.x * blockDim.x + threadIdx.x;
  if (t >= total) return;
  int l = t & 63;
  int rest = t >> 6;
  int kt = rest % KT, ct = rest / KT;
  int col = ct * 16 + (l & 15);
  int k0 = kt * 32 + (l >> 4) * 8;
  s8v v;
#pragma unroll
  for (int b = 0; b < 8; ++b) v[b] = (short)f2bf(W[(size_t)(k0 + b) * NC + col]);
  *reinterpret_cast<s8v*>(&Wf[(size_t)t * 8]) = v;
}

// ---------------- gather aggregation (one wave per dst row, bf16 in/out) ----------------
// out[d] = dscale[d] * ( selfterm + sum_{j in CSR[d]} sscale[col_j] * src[col_j] )
// selfmode: 0 none, 1 unit (src[d]), 2 selfs[d]*src[d]
__global__ __launch_bounds__(256) void k_gather(
    const unsigned short* __restrict__ src, const float* __restrict__ sscale,
    const float* __restrict__ selfs, int selfmode, const float* __restrict__ dscale,
    const int* __restrict__ off, const int* __restrict__ endp,
    const int* __restrict__ colv, unsigned short* __restrict__ out, int n) {
  int tid = threadIdx.x;
  int row = blockIdx.x * 4 + (tid >> 6);
  if (row >= n) return;
  int l = tid & 63;
  const ushort2* s2 = reinterpret_cast<const ushort2*>(src);
  float ax = 0.f, ay = 0.f;
  if (selfmode) {
    float ss = (selfmode == 2) ? selfs[row] : 1.0f;
    ushort2 u = s2[(size_t)row * 64 + l];
    ax = bf2f(u.x) * ss; ay = bf2f(u.y) * ss;
  }
  int j0 = off[row], j1 = endp[row];
  if (sscale) {
    for (int j = j0; j < j1; ++j) {
      int s = colv[j];
      float sc = sscale[s];
      ushort2 u = s2[(size_t)s * 64 + l];
      ax += bf2f(u.x) * sc; ay += bf2f(u.y) * sc;
    }
  } else {
    for (int j = j0; j < j1; ++j) {
      int s = colv[j];
      ushort2 u = s2[(size_t)s * 64 + l];
      ax += bf2f(u.x); ay += bf2f(u.y);
    }
  }
  if (dscale) { float dsc = dscale[row]; ax *= dsc; ay *= dsc; }
  ushort2 o; o.x = f2bf(ax); o.y = f2bf(ay);
  reinterpret_cast<ushort2*>(out)[(size_t)row * 64 + l] = o;
}

// ---------------- fused MFMA GEMM1 + bias + relu + LN + GEMM2 ----------------
// in: bf16 [n][128]; T = LN(relu(in@W1 + b1)); out = bf16( (T@W2) * (os ? os[row] : 1) )
// W1f/W2f: fragment-ordered bf16 (k_wfrag layout). BM=32 rows/block, 4 waves.
__global__ __launch_bounds__(256) void k_fused_gemm_mfma(
    const unsigned short* __restrict__ in,
    const unsigned short* __restrict__ W1f, const float* __restrict__ b1,
    const float* __restrict__ g1, const float* __restrict__ be1,
    const unsigned short* __restrict__ W2f, const float* __restrict__ os,
    unsigned short* __restrict__ out, int n) {
  __shared__ __align__(16) unsigned short Xl[BM * PX];
  __shared__ __align__(16) unsigned short Tl[BM * PT];
  __shared__ float red[4][BM], redq[4][BM];
  __shared__ float smean[BM], srstd[BM];
  int tid = threadIdx.x;
  int w = tid >> 6, l = tid & 63;
  int row0 = blockIdx.x * BM;

  // stage X: 32 rows x 128 bf16 (coalesced; 16 bf16 per thread)
  {
    int r = tid >> 3, seg = tid & 7;
    int row = row0 + r;
    s8v v0 = {}, v1 = {};
    if (row < n) {
      const s8v* src = reinterpret_cast<const s8v*>(in + (size_t)row * HD + seg * 16);
      v0 = src[0]; v1 = src[1];
    }
    *reinterpret_cast<s8v*>(&Xl[r * PX + seg * 16]) = v0;
    *reinterpret_cast<s8v*>(&Xl[r * PX + seg * 16 + 8]) = v1;
  }
  __syncthreads();

  // ---- GEMM1: [32x128] @ [128x256]; wave w covers cols w*64..w*64+63 ----
  f4v zz = {0.f, 0.f, 0.f, 0.f};
  f4v acc1[2][4];
#pragma unroll
  for (int rt = 0; rt < 2; ++rt)
#pragma unroll
    for (int c = 0; c < 4; ++c) acc1[rt][c] = zz;

#pragma unroll
  for (int kt = 0; kt < 4; ++kt) {
    s8v a0 = *reinterpret_cast<const s8v*>(&Xl[(l & 15) * PX + kt * 32 + (l >> 4) * 8]);
    s8v a1 = *reinterpret_cast<const s8v*>(&Xl[((l & 15) + 16) * PX + kt * 32 + (l >> 4) * 8]);
#pragma unroll
    for (int c = 0; c < 4; ++c) {
      int ct = w * 4 + c;
      s8v bf = *reinterpret_cast<const s8v*>(&W1f[((size_t)(ct * 4 + kt) * 64 + l) * 8]);
      acc1[0][c] = __builtin_amdgcn_mfma_f32_16x16x32_bf16(a0, bf, acc1[0][c], 0, 0, 0);
      acc1[1][c] = __builtin_amdgcn_mfma_f32_16x16x32_bf16(a1, bf, acc1[1][c], 0, 0, 0);
    }
  }

  // bias + relu (D layout: col = ct*16 + (l&15), row = rt*16 + (l>>4)*4 + r)
  float b1c[4], g1c[4], e1c[4];
#pragma unroll
  for (int c = 0; c < 4; ++c) {
    int col = w * 64 + c * 16 + (l & 15);
    b1c[c] = b1[col]; g1c[c] = g1[col]; e1c[c] = be1[col];
  }
#pragma unroll
  for (int rt = 0; rt < 2; ++rt)
#pragma unroll
    for (int c = 0; c < 4; ++c)
#pragma unroll
      for (int r = 0; r < 4; ++r)
        acc1[rt][c][r] = fmaxf(acc1[rt][c][r] + b1c[c], 0.f);

  // LN stats: reduce 4 cols in-reg, then xor-shuffle low 4 lane bits, then cross-wave in LDS
#pragma unroll
  for (int rt = 0; rt < 2; ++rt)
#pragma unroll
    for (int r = 0; r < 4; ++r) {
      float s = acc1[rt][0][r] + acc1[rt][1][r] + acc1[rt][2][r] + acc1[rt][3][r];
      float q = acc1[rt][0][r] * acc1[rt][0][r] + acc1[rt][1][r] * acc1[rt][1][r] +
                acc1[rt][2][r] * acc1[rt][2][r] + acc1[rt][3][r] * acc1[rt][3][r];
#pragma unroll
      for (int off = 1; off <= 8; off <<= 1) { s += __shfl_xor(s, off); q += __shfl_xor(q, off); }
      if ((l & 15) == 0) {
        int row = rt * 16 + (l >> 4) * 4 + r;
        red[w][row] = s; redq[w][row] = q;
      }
    }
  __syncthreads();
  if (tid < BM) {
    float S = red[0][tid] + red[1][tid] + red[2][tid] + red[3][tid];
    float Q = redq[0][tid] + redq[1][tid] + redq[2][tid] + redq[3][tid];
    float mean = S * (1.0f / HD2);
    float var = Q * (1.0f / HD2) - mean * mean;
    smean[tid] = mean;
    srstd[tid] = rsqrtf(var + LN_EPS);
  }
  __syncthreads();

  // apply LN, write normalized tile to Tl (bf16)
#pragma unroll
  for (int rt = 0; rt < 2; ++rt)
#pragma unroll
    for (int c = 0; c < 4; ++c)
#pragma unroll
      for (int r = 0; r < 4; ++r) {
        int row = rt * 16 + (l >> 4) * 4 + r;
        int col = w * 64 + c * 16 + (l & 15);
        float t = (acc1[rt][c][r] - smean[row]) * srstd[row] * g1c[c] + e1c[c];
        Tl[row * PT + col] = f2bf(t);
      }
  __syncthreads();

  // ---- GEMM2: [32x256] @ [256x128]; wave w covers cols w*32..w*32+31 ----
  f4v acc2[2][2];
#pragma unroll
  for (int rt = 0; rt < 2; ++rt)
#pragma unroll
    for (int c = 0; c < 2; ++c) acc2[rt][c] = zz;

#pragma unroll
  for (int kt = 0; kt < 8; ++kt) {
    s8v a0 = *reinterpret_cast<const s8v*>(&Tl[(l & 15) * PT + kt * 32 + (l >> 4) * 8]);
    s8v a1 = *reinterpret_cast<const s8v*>(&Tl[((l & 15) + 16) * PT + kt * 32 + (l >> 4) * 8]);
#pragma unroll
    for (int c = 0; c < 2; ++c) {
      int ct2 = w * 2 + c;
      s8v bf = *reinterpret_cast<const s8v*>(&W2f[((size_t)(ct2 * 8 + kt) * 64 + l) * 8]);
      acc2[0][c] = __builtin_amdgcn_mfma_f32_16x16x32_bf16(a0, bf, acc2[0][c], 0, 0, 0);
      acc2[1][c] = __builtin_amdgcn_mfma_f32_16x16x32_bf16(a1, bf, acc2[1][c], 0, 0, 0);
    }
  }

  // store (optionally row-scaled), bf16
#pragma unroll
  for (int rt = 0; rt < 2; ++rt)
#pragma unroll
    for (int r = 0; r < 4; ++r) {
      int row = row0 + rt * 16 + (l >> 4) * 4 + r;
      if (row < n) {
        float sc = os ? os[row] : 1.0f;
#pragma unroll
        for (int c = 0; c < 2; ++c)
          out[(size_t)row * HD + (w * 2 + c) * 16 + (l & 15)] = f2bf(acc2[rt][c][r] * sc);
      }
    }
}

// out[row] = LN(relu(in[row]*s[row] + bias)); in bf16. OUTBF=1 -> bf16 out, else f32.
template <int OUTBF>
__global__ __launch_bounds__(256) void k_final_ln(
    const unsigned short* __restrict__ in, const float* __restrict__ s,
    const float* __restrict__ bias, const float* __restrict__ g,
    const float* __restrict__ be, void* __restrict__ outp, int n) {
  int tid = threadIdx.x;
  int row = blockIdx.x * 4 + (tid >> 6);
  if (row >= n) return;
  int l = tid & 63;
  float sc = s[row];
  ushort2 u = reinterpret_cast<const ushort2*>(in)[(size_t)row * 64 + l];
  float2 bb = reinterpret_cast<const float2*>(bias)[l];
  float x0 = fmaxf(bf2f(u.x) * sc + bb.x, 0.f);
  float x1 = fmaxf(bf2f(u.y) * sc + bb.y, 0.f);
  float sum = waveReduceSum(x0 + x1);
  float sq  = waveReduceSum(x0 * x0 + x1 * x1);
  float mean = sum * (1.0f / HD);
  float var = sq * (1.0f / HD) - mean * mean;
  float rstd = rsqrtf(var + LN_EPS);
  float2 gg = reinterpret_cast<const float2*>(g)[l];
  float2 bbe = reinterpret_cast<const float2*>(be)[l];
  float o0 = (x0 - mean) * rstd * gg.x + bbe.x;
  float o1 = (x1 - mean) * rstd * gg.y + bbe.y;
  if (OUTBF) {
    ushort2 o; o.x = f2bf(o0); o.y = f2bf(o1);
    reinterpret_cast<ushort2*>(outp)[(size_t)row * 64 + l] = o;
  } else {
    float2 o; o.x = o0; o.y = o1;
    reinterpret_cast<float2*>(outp)[(size_t)row * 64 + l] = o;
  }
}

// Per-node 3-key attention + LN. x1,x2 bf16; x3 f32 (in-place with out ok).
__global__ __launch_bounds__(256) void k_fuse(
    const float* __restrict__ emb, const unsigned short* __restrict__ x1,
    const unsigned short* __restrict__ x2, const float* __restrict__ x3,
    const float* __restrict__ g, const float* __restrict__ be,
    float* __restrict__ out, int n) {
  int tid = threadIdx.x;
  int row = blockIdx.x * 4 + (tid >> 6);
  if (row >= n) return;
  int l = tid & 63;
  size_t base = (size_t)row * 64 + l;
  float2 q = reinterpret_cast<const float2*>(emb)[base];
  ushort2 u1 = reinterpret_cast<const ushort2*>(x1)[base];
  ushort2 u2 = reinterpret_cast<const ushort2*>(x2)[base];
  float2 a = make_float2(bf2f(u1.x), bf2f(u1.y));
  float2 b = make_float2(bf2f(u2.x), bf2f(u2.y));
  float2 c = reinterpret_cast<const float2*>(x3)[base];
  float d1 = waveReduceSum(q.x * a.x + q.y * a.y);
  float d2 = waveReduceSum(q.x * b.x + q.y * b.y);
  float d3 = waveReduceSum(q.x * c.x + q.y * c.y);
  const float is = 0.088388347648318447f; // 1/sqrt(128)
  float s1 = d1 * is, s2 = d2 * is, s3 = d3 * is;
  float m = fmaxf(s1, fmaxf(s2, s3));
  float p1 = expf(s1 - m), p2 = expf(s2 - m), p3 = expf(s3 - m);
  float den = 1.0f / (p1 + p2 + p3);
  p1 *= den; p2 *= den; p3 *= den;
  float ox = p1 * a.x + p2 * b.x + p3 * c.x;
  float oy = p1 * a.y + p2 * b.y + p3 * c.y;
  float sum = waveReduceSum(ox + oy);
  float sq  = waveReduceSum(ox * ox + oy * oy);
  float mean = sum * (1.0f / HD);
  float var = sq * (1.0f / HD) - mean * mean;
  float rstd = rsqrtf(var + LN_EPS);
  float2 gg = reinterpret_cast<const float2*>(g)[l];
  float2 bb = reinterpret_cast<const float2*>(be)[l];
  float2 o;
  o.x = (ox - mean) * rstd * gg.x + bb.x;
  o.y = (oy - mean) * rstd * gg.y + bb.y;
  reinterpret_cast<float2*>(out)[base] = o;
}

extern "C" void kernel_launch(void* const* d_in, const int* in_sizes, int n_in,
                              void* d_out, int out_size, void* d_ws, size_t ws_size,
                              hipStream_t stream) {
  (void)n_in; (void)out_size; (void)ws_size;
  const float* emb  = (const float*)d_in[0];
  const int* e_soc  = (const int*)d_in[1];
  const int* e_dif  = (const int*)d_in[2];
  const int* e_hyp  = (const int*)d_in[3];
  const float* fuse_g = (const float*)d_in[4];
  const float* fuse_b = (const float*)d_in[5];
  const int N  = in_sizes[0] / HD;
  const int E1 = in_sizes[1] / 2;
  const int E2 = in_sizes[2] / 2;
  const int E3 = in_sizes[3] / 2;
  float* dout = (float*)d_out;

  // ---- workspace carve-up (~135 MB) ----
  char* wsb = (char*)d_ws;
  size_t o = 0;
  auto alloc = [&](size_t bytes) { void* p = wsb + o; o = (o + bytes + 15) & ~(size_t)15; return p; };
  int* deg_soc = (int*)alloc((size_t)4 * N * 4);
  int* deg_dif = deg_soc + N;
  int* deg_hn  = deg_soc + 2 * (size_t)N;
  int* deg_he  = deg_soc + 3 * (size_t)N;
  int* cur_soc = (int*)alloc((size_t)4 * N * 4);
  int* cur_dif = cur_soc + N;
  int* cur_hn  = cur_soc + 2 * (size_t)N;
  int* cur_he  = cur_soc + 3 * (size_t)N;
  int* off_soc = (int*)alloc((size_t)4 * N * 4);
  int* off_dif = off_soc + N;
  int* off_hn  = off_soc + 2 * (size_t)N;
  int* off_he  = off_soc + 3 * (size_t)N;
  int* bsum4  = (int*)alloc(4 * 1024 * 4);
  int* bbase4 = (int*)alloc(4 * 1024 * 4);
  int* col_soc = (int*)alloc((size_t)E1 * 4);
  int* col_dif = (int*)alloc((size_t)E2 * 4);
  int* col_hn  = (int*)alloc((size_t)E3 * 4);
  int* col_he  = (int*)alloc((size_t)E3 * 4);
  float* dsoc = (float*)alloc((size_t)N * 4);
  float* ddif = (float*)alloc((size_t)N * 4);
  float* Dinv = (float*)alloc((size_t)N * 4);
  float* Binv = (float*)alloc((size_t)N * 4);
  unsigned short* Wf1 = (unsigned short*)alloc((size_t)HD * HD2 * 2);
  unsigned short* Wf2 = (unsigned short*)alloc((size_t)HD2 * HD * 2);
  unsigned short* emb_bf = (unsigned short*)alloc((size_t)N * HD * 2);
  unsigned short* A_bf   = (unsigned short*)alloc((size_t)N * HD * 2);
  unsigned short* B_bf   = (unsigned short*)alloc((size_t)N * HD * 2);
  unsigned short* X1     = (unsigned short*)alloc((size_t)N * HD * 2);
  unsigned short* X2     = (unsigned short*)alloc((size_t)N * HD * 2);

  const int NB = (N + 255) / 256;
  int gN   = (N + 255) / 256;
  int gRow = (N + 3) / 4;
  int gG   = (N + BM - 1) / BM;
  const int WF1_TOT = (HD2 / 16) * (HD / 32) * 64;   // 4096
  const int WF2_TOT = (HD / 16) * (HD2 / 32) * 64;   // 4096

  // ---- degrees ----
  k_izero<<<(4 * N + 255) / 256, 256, 0, stream>>>(deg_soc, 4 * N);
  k_icount<<<(E1 + 255) / 256, 256, 0, stream>>>(e_soc + E1, deg_soc, E1);
  k_icount<<<(E2 + 255) / 256, 256, 0, stream>>>(e_dif + E2, deg_dif, E2);
  k_icount<<<(E3 + 255) / 256, 256, 0, stream>>>(e_hyp,      deg_hn,  E3);
  k_icount<<<(E3 + 255) / 256, 256, 0, stream>>>(e_hyp + E3, deg_he,  E3);
  k_norms<<<gN, 256, 0, stream>>>(deg_soc, deg_dif, deg_hn, deg_he, dsoc, ddif, Dinv, Binv, N);

  // ---- CSR offsets + columns (4 graphs) ----
  const int* degs[4] = {deg_soc, deg_dif, deg_hn, deg_he};
  int* curs[4] = {cur_soc, cur_dif, cur_hn, cur_he};
  int* offs[4] = {off_soc, off_dif, off_hn, off_he};
  for (int g = 0; g < 4; ++g) {
    k_bsum<<<NB, 256, 0, stream>>>(degs[g], bsum4 + g * 1024, N);
    k_scanblk<<<1, 1024, 0, stream>>>(bsum4 + g * 1024, bbase4 + g * 1024, NB);
    k_fillof<<<NB, 256, 0, stream>>>(degs[g], bbase4 + g * 1024, offs[g], curs[g], N);
  }
  k_fillcol<<<(E1 + 255) / 256, 256, 0, stream>>>(e_soc,      e_soc + E1, cur_soc, col_soc, E1);
  k_fillcol<<<(E2 + 255) / 256, 256, 0, stream>>>(e_dif,      e_dif + E2, cur_dif, col_dif, E2);
  k_fillcol<<<(E3 + 255) / 256, 256, 0, stream>>>(e_hyp + E3, e_hyp,      cur_hn,  col_hn,  E3); // node -> hes
  k_fillcol<<<(E3 + 255) / 256, 256, 0, stream>>>(e_hyp,      e_hyp + E3, cur_he,  col_he,  E3); // he -> nodes

  // ---- emb -> bf16 once ----
  k_cvt<<<(N * HD / 4 + 255) / 256, 256, 0, stream>>>(emb, emb_bf, N * HD / 4);

  // ---- two GCN paths (soc -> X1, dif -> X2) ----
  for (int p = 0; p < 2; ++p) {
    float* dinv = (p == 0) ? dsoc : ddif;
    const int* off = offs[p];
    const int* end = curs[p];
    const int* col = (p == 0) ? col_soc : col_dif;
    unsigned short* Xp = (p == 0) ? X1 : X2;
    const float* W1  = (const float*)d_in[6 + p * 8 + 0];
    const float* b1  = (const float*)d_in[6 + p * 8 + 1];
    const float* g1  = (const float*)d_in[6 + p * 8 + 2];
    const float* be1 = (const float*)d_in[6 + p * 8 + 3];
    const float* W2  = (const float*)d_in[6 + p * 8 + 4];
    const float* b2  = (const float*)d_in[6 + p * 8 + 5];
    const float* g2  = (const float*)d_in[6 + p * 8 + 6];
    const float* be2 = (const float*)d_in[6 + p * 8 + 7];

    k_wfrag<<<(WF1_TOT + 255) / 256, 256, 0, stream>>>(W1, Wf1, HD / 32, HD2, WF1_TOT);
    k_wfrag<<<(WF2_TOT + 255) / 256, 256, 0, stream>>>(W2, Wf2, HD2 / 32, HD, WF2_TOT);

    // layer1 aggregation with both scales folded: A = dinv[d]*(Σ dinv[s]x[s] + dinv[d]x[d])
    k_gather<<<gRow, 256, 0, stream>>>(emb_bf, dinv, dinv, 2, dinv, off, end, col, A_bf, N);
    k_fused_gemm_mfma<<<gG, 256, 0, stream>>>(A_bf, Wf1, b1, g1, be1, Wf2, dinv, B_bf, N);
    k_gather<<<gRow, 256, 0, stream>>>(B_bf, nullptr, nullptr, 1, nullptr, off, end, col, A_bf, N);
    k_final_ln<1><<<gRow, 256, 0, stream>>>(A_bf, dinv, b2, g2, be2, Xp, N);
  }

  // ---- HGNN path (hyp -> dout) ----
  {
    const float* W1  = (const float*)d_in[22 + 0];
    const float* b1  = (const float*)d_in[22 + 1];
    const float* g1  = (const float*)d_in[22 + 2];
    const float* be1 = (const float*)d_in[22 + 3];
    const float* W2  = (const float*)d_in[22 + 4];
    const float* b2  = (const float*)d_in[22 + 5];
    const float* g2  = (const float*)d_in[22 + 6];
    const float* be2 = (const float*)d_in[22 + 7];

    k_wfrag<<<(WF1_TOT + 255) / 256, 256, 0, stream>>>(W1, Wf1, HD / 32, HD2, WF1_TOT);
    k_wfrag<<<(WF2_TOT + 255) / 256, 256, 0, stream>>>(W2, Wf2, HD2 / 32, HD, WF2_TOT);

    // He = Binv * Σ_node emb ; Bv = Dinv * Σ_he He
    k_gather<<<gRow, 256, 0, stream>>>(emb_bf, nullptr, nullptr, 0, Binv, off_he, cur_he, col_he, A_bf, N);
    k_gather<<<gRow, 256, 0, stream>>>(A_bf, nullptr, nullptr, 0, Dinv, off_hn, cur_hn, col_hn, B_bf, N);
    k_fused_gemm_mfma<<<gG, 256, 0, stream>>>(B_bf, Wf1, b1, g1, be1, Wf2, nullptr, A_bf, N);
    k_gather<<<gRow, 256, 0, stream>>>(A_bf, nullptr, nullptr, 0, Binv, off_he, cur_he, col_he, B_bf, N);
    k_gather<<<gRow, 256, 0, stream>>>(B_bf, nullptr, nullptr, 0, nullptr, off_hn, cur_hn, col_hn, A_bf, N);
    k_final_ln<0><<<gRow, 256, 0, stream>>>(A_bf, Dinv, b2, g2, be2, dout, N);
  }

  // ---- fusion attention + LN -> d_out (in-place over X3) ----
  k_fuse<<<gRow, 256, 0, stream>>>(emb, X1, X2, dout, fuse_g, fuse_b, dout, N);
}

// Round 6
// 750.300 us; speedup vs baseline: 4.6241x; 1.2245x over previous
//
#include <hip/hip_runtime.h>
#include <math.h>

#define HD   128
#define HD2  256
#define LN_EPS 1e-5f
#define BM 32
#define PX 136   // X LDS pitch in bf16 elems (128 + 8 pad)
#define PT 264   // T LDS pitch in bf16 elems (256 + 8 pad)

typedef __attribute__((ext_vector_type(8))) short s8v;    // 8 x bf16 (4 VGPR)
typedef __attribute__((ext_vector_type(4))) float f4v;    // MFMA acc

static __device__ __forceinline__ float waveReduceSum(float v) {
#pragma unroll
  for (int off = 32; off >= 1; off >>= 1) v += __shfl_xor(v, off);
  return v;
}

static __device__ __forceinline__ float bf2f(unsigned short u) {
  union { unsigned int i; float f; } c; c.i = ((unsigned int)u) << 16; return c.f;
}

static __device__ __forceinline__ unsigned short f2bf(float f) {
  union { float f; unsigned int i; } c; c.f = f;
  unsigned int lsb = (c.i >> 16) & 1u;
  return (unsigned short)((c.i + 0x7fffu + lsb) >> 16);
}

// ---------------- CSR build ----------------
__global__ void k_izero(int* __restrict__ p, int n) {
  int i = blockIdx.x * blockDim.x + threadIdx.x;
  if (i < n) p[i] = 0;
}

__global__ void k_icount(const int* __restrict__ idx, int* __restrict__ deg, int e) {
  int i = blockIdx.x * blockDim.x + threadIdx.x;
  if (i < e) atomicAdd(&deg[idx[i]], 1);
}

__global__ void k_norms(const int* __restrict__ cs, const int* __restrict__ cd,
                        const int* __restrict__ chn, const int* __restrict__ che,
                        float* __restrict__ dsoc, float* __restrict__ ddif,
                        float* __restrict__ Dinv, float* __restrict__ Binv, int n) {
  int i = blockIdx.x * blockDim.x + threadIdx.x;
  if (i >= n) return;
  dsoc[i] = rsqrtf((float)(cs[i] + 1));
  ddif[i] = rsqrtf((float)(cd[i] + 1));
  int dn = chn[i]; Dinv[i] = dn > 0 ? 1.0f / (float)dn : 0.0f;
  int bh = che[i]; Binv[i] = bh > 0 ? 1.0f / (float)bh : 0.0f;
}

__global__ __launch_bounds__(256) void k_bsum(const int* __restrict__ deg,
                                              int* __restrict__ bsum, int n) {
  __shared__ int sh[256];
  int t = threadIdx.x;
  int i = blockIdx.x * 256 + t;
  sh[t] = (i < n) ? deg[i] : 0;
  __syncthreads();
  for (int d = 128; d > 0; d >>= 1) { if (t < d) sh[t] += sh[t + d]; __syncthreads(); }
  if (t == 0) bsum[blockIdx.x] = sh[0];
}

__global__ __launch_bounds__(1024) void k_scanblk(const int* __restrict__ bsum,
                                                  int* __restrict__ bbase, int nb) {
  __shared__ int sh[1024];
  int t = threadIdx.x;
  int v = (t < nb) ? bsum[t] : 0;
  sh[t] = v;
  __syncthreads();
  for (int d = 1; d < 1024; d <<= 1) {
    int x = (t >= d) ? sh[t - d] : 0;
    __syncthreads();
    sh[t] += x;
    __syncthreads();
  }
  if (t < nb) bbase[t] = sh[t] - v;   // exclusive
}

__global__ __launch_bounds__(256) void k_fillof(const int* __restrict__ deg,
                                                const int* __restrict__ bbase,
                                                int* __restrict__ off, int* __restrict__ cur,
                                                int n) {
  __shared__ int sh[256];
  int t = threadIdx.x;
  int i = blockIdx.x * 256 + t;
  int v = (i < n) ? deg[i] : 0;
  sh[t] = v;
  __syncthreads();
  for (int d = 1; d < 256; d <<= 1) {
    int x = (t >= d) ? sh[t - d] : 0;
    __syncthreads();
    sh[t] += x;
    __syncthreads();
  }
  if (i < n) { int e = bbase[blockIdx.x] + sh[t] - v; off[i] = e; cur[i] = e; }
}

__global__ void k_fillcol(const int* __restrict__ sidx, const int* __restrict__ didx,
                          int* __restrict__ cur, int* __restrict__ colv, int e) {
  int i = blockIdx.x * blockDim.x + threadIdx.x;
  if (i < e) {
    int d = didx[i];
    int slot = atomicAdd(&cur[d], 1);
    colv[slot] = sidx[i];
  }
}

// fp32 -> bf16 bulk convert (vectorized)
__global__ void k_cvt(const float* __restrict__ in, unsigned short* __restrict__ out, int n4) {
  int i = blockIdx.x * blockDim.x + threadIdx.x;
  if (i < n4) {
    float4 v = reinterpret_cast<const float4*>(in)[i];
    ushort4 o;
    o.x = f2bf(v.x); o.y = f2bf(v.y); o.z = f2bf(v.z); o.w = f2bf(v.w);
    reinterpret_cast<ushort4*>(out)[i] = o;
  }
}

// W [K][NC] fp32 -> fragment-ordered bf16: Wf[((ct*KT+kt)*64+l)*8+b] = W[kt*32+(l>>4)*8+b][ct*16+(l&15)]
__global__ void k_wfrag(const float* __restrict__ W, unsigned short* __restrict__ Wf,
                        int KT, int NC, int total) {
  int t = blockIdx.x * blockDim.x + threadIdx.x;
  if (t >= total) return;
  int l = t & 63;
  int rest = t >> 6;
  int kt = rest % KT, ct = rest / KT;
  int col = ct * 16 + (l & 15);
  int k0 = kt * 32 + (l >> 4) * 8;
  s8v v;
#pragma unroll
  for (int b = 0; b < 8; ++b) v[b] = (short)f2bf(W[(size_t)(k0 + b) * NC + col]);
  *reinterpret_cast<s8v*>(&Wf[(size_t)t * 8]) = v;
}

// ---------------- gather: 4 rows per wave, interleaved edge chains ----------------
// acc[d] = selfterm + sum_{j in CSR[d]} sscale[col_j] * src[col_j]
// LNEPI 0: out = bf16(acc * dscale[d])
// LNEPI 1: out = bf16( LN(relu(acc*dscale + lnb)) * lng + lnbe )
// LNEPI 2: same but f32 out
template <int LNEPI>
__global__ __launch_bounds__(256) void k_gather4(
    const unsigned short* __restrict__ src, const float* __restrict__ sscale,
    const float* __restrict__ selfs, int selfmode, const float* __restrict__ dscale,
    const int* __restrict__ off, const int* __restrict__ endp,
    const int* __restrict__ colv,
    const float* __restrict__ lnb, const float* __restrict__ lng,
    const float* __restrict__ lnbe, void* __restrict__ outp, int n) {
  int tid = threadIdx.x;
  int w = tid >> 6, l = tid & 63;
  int row0 = blockIdx.x * 16 + w * 4;
  const ushort2* s2 = reinterpret_cast<const ushort2*>(src);
  float ax[4] = {0.f, 0.f, 0.f, 0.f}, ay[4] = {0.f, 0.f, 0.f, 0.f};
  int jj[4], ee[4];
#pragma unroll
  for (int r = 0; r < 4; ++r) {
    int row = row0 + r;
    bool v = row < n;
    jj[r] = v ? off[row] : 0;
    ee[r] = v ? endp[row] : 0;
    if (selfmode && v) {
      float ss = (selfmode == 2) ? selfs[row] : 1.0f;
      ushort2 u = s2[(size_t)row * 64 + l];
      ax[r] = bf2f(u.x) * ss; ay[r] = bf2f(u.y) * ss;
    }
  }
  // joint branch-free loop: 4 independent load chains per wave
  while (true) {
    bool a0 = jj[0] < ee[0], a1 = jj[1] < ee[1], a2 = jj[2] < ee[2], a3 = jj[3] < ee[3];
    if (!(a0 || a1 || a2 || a3)) break;
    int i0 = a0 ? jj[0] : 0, i1 = a1 ? jj[1] : 0, i2 = a2 ? jj[2] : 0, i3 = a3 ? jj[3] : 0;
    int s0 = colv[i0], s1 = colv[i1], s2i = colv[i2], s3 = colv[i3];
    ushort2 u0 = s2[(size_t)s0 * 64 + l];
    ushort2 u1 = s2[(size_t)s1 * 64 + l];
    ushort2 u2 = s2[(size_t)s2i * 64 + l];
    ushort2 u3 = s2[(size_t)s3 * 64 + l];
    float w0, w1, w2, w3;
    if (sscale) {
      w0 = a0 ? sscale[s0] : 0.f; w1 = a1 ? sscale[s1] : 0.f;
      w2 = a2 ? sscale[s2i] : 0.f; w3 = a3 ? sscale[s3] : 0.f;
    } else {
      w0 = a0 ? 1.f : 0.f; w1 = a1 ? 1.f : 0.f; w2 = a2 ? 1.f : 0.f; w3 = a3 ? 1.f : 0.f;
    }
    ax[0] += bf2f(u0.x) * w0; ay[0] += bf2f(u0.y) * w0;
    ax[1] += bf2f(u1.x) * w1; ay[1] += bf2f(u1.y) * w1;
    ax[2] += bf2f(u2.x) * w2; ay[2] += bf2f(u2.y) * w2;
    ax[3] += bf2f(u3.x) * w3; ay[3] += bf2f(u3.y) * w3;
    jj[0] += a0; jj[1] += a1; jj[2] += a2; jj[3] += a3;
  }

  float2 bb = {0.f, 0.f}, gg = {0.f, 0.f}, eb = {0.f, 0.f};
  if (LNEPI) {
    bb = reinterpret_cast<const float2*>(lnb)[l];
    gg = reinterpret_cast<const float2*>(lng)[l];
    eb = reinterpret_cast<const float2*>(lnbe)[l];
  }
#pragma unroll
  for (int r = 0; r < 4; ++r) {
    int row = row0 + r;
    if (row >= n) continue;
    float sc = dscale ? dscale[row] : 1.0f;
    if (LNEPI == 0) {
      ushort2 o; o.x = f2bf(ax[r] * sc); o.y = f2bf(ay[r] * sc);
      reinterpret_cast<ushort2*>(outp)[(size_t)row * 64 + l] = o;
    } else {
      float x0 = fmaxf(ax[r] * sc + bb.x, 0.f);
      float x1 = fmaxf(ay[r] * sc + bb.y, 0.f);
      float sum = waveReduceSum(x0 + x1);
      float sq  = waveReduceSum(x0 * x0 + x1 * x1);
      float mean = sum * (1.0f / HD);
      float var = sq * (1.0f / HD) - mean * mean;
      float rstd = rsqrtf(var + LN_EPS);
      float o0 = (x0 - mean) * rstd * gg.x + eb.x;
      float o1 = (x1 - mean) * rstd * gg.y + eb.y;
      if (LNEPI == 1) {
        ushort2 o; o.x = f2bf(o0); o.y = f2bf(o1);
        reinterpret_cast<ushort2*>(outp)[(size_t)row * 64 + l] = o;
      } else {
        float2 o; o.x = o0; o.y = o1;
        reinterpret_cast<float2*>(outp)[(size_t)row * 64 + l] = o;
      }
    }
  }
}

// ---------------- fused MFMA GEMM1 + bias + relu + LN + GEMM2 ----------------
__global__ __launch_bounds__(256) void k_fused_gemm_mfma(
    const unsigned short* __restrict__ in,
    const unsigned short* __restrict__ W1f, const float* __restrict__ b1,
    const float* __restrict__ g1, const float* __restrict__ be1,
    const unsigned short* __restrict__ W2f, const float* __restrict__ os,
    unsigned short* __restrict__ out, int n) {
  __shared__ __align__(16) unsigned short Xl[BM * PX];
  __shared__ __align__(16) unsigned short Tl[BM * PT];
  __shared__ float red[4][BM], redq[4][BM];
  __shared__ float smean[BM], srstd[BM];
  int tid = threadIdx.x;
  int w = tid >> 6, l = tid & 63;
  int row0 = blockIdx.x * BM;

  {
    int r = tid >> 3, seg = tid & 7;
    int row = row0 + r;
    s8v v0 = {}, v1 = {};
    if (row < n) {
      const s8v* src = reinterpret_cast<const s8v*>(in + (size_t)row * HD + seg * 16);
      v0 = src[0]; v1 = src[1];
    }
    *reinterpret_cast<s8v*>(&Xl[r * PX + seg * 16]) = v0;
    *reinterpret_cast<s8v*>(&Xl[r * PX + seg * 16 + 8]) = v1;
  }
  __syncthreads();

  f4v zz = {0.f, 0.f, 0.f, 0.f};
  f4v acc1[2][4];
#pragma unroll
  for (int rt = 0; rt < 2; ++rt)
#pragma unroll
    for (int c = 0; c < 4; ++c) acc1[rt][c] = zz;

#pragma unroll
  for (int kt = 0; kt < 4; ++kt) {
    s8v a0 = *reinterpret_cast<const s8v*>(&Xl[(l & 15) * PX + kt * 32 + (l >> 4) * 8]);
    s8v a1 = *reinterpret_cast<const s8v*>(&Xl[((l & 15) + 16) * PX + kt * 32 + (l >> 4) * 8]);
#pragma unroll
    for (int c = 0; c < 4; ++c) {
      int ct = w * 4 + c;
      s8v bf = *reinterpret_cast<const s8v*>(&W1f[((size_t)(ct * 4 + kt) * 64 + l) * 8]);
      acc1[0][c] = __builtin_amdgcn_mfma_f32_16x16x32_bf16(a0, bf, acc1[0][c], 0, 0, 0);
      acc1[1][c] = __builtin_amdgcn_mfma_f32_16x16x32_bf16(a1, bf, acc1[1][c], 0, 0, 0);
    }
  }

  float b1c[4], g1c[4], e1c[4];
#pragma unroll
  for (int c = 0; c < 4; ++c) {
    int col = w * 64 + c * 16 + (l & 15);
    b1c[c] = b1[col]; g1c[c] = g1[col]; e1c[c] = be1[col];
  }
#pragma unroll
  for (int rt = 0; rt < 2; ++rt)
#pragma unroll
    for (int c = 0; c < 4; ++c)
#pragma unroll
      for (int r = 0; r < 4; ++r)
        acc1[rt][c][r] = fmaxf(acc1[rt][c][r] + b1c[c], 0.f);

#pragma unroll
  for (int rt = 0; rt < 2; ++rt)
#pragma unroll
    for (int r = 0; r < 4; ++r) {
      float s = acc1[rt][0][r] + acc1[rt][1][r] + acc1[rt][2][r] + acc1[rt][3][r];
      float q = acc1[rt][0][r] * acc1[rt][0][r] + acc1[rt][1][r] * acc1[rt][1][r] +
                acc1[rt][2][r] * acc1[rt][2][r] + acc1[rt][3][r] * acc1[rt][3][r];
#pragma unroll
      for (int off = 1; off <= 8; off <<= 1) { s += __shfl_xor(s, off); q += __shfl_xor(q, off); }
      if ((l & 15) == 0) {
        int row = rt * 16 + (l >> 4) * 4 + r;
        red[w][row] = s; redq[w][row] = q;
      }
    }
  __syncthreads();
  if (tid < BM) {
    float S = red[0][tid] + red[1][tid] + red[2][tid] + red[3][tid];
    float Q = redq[0][tid] + redq[1][tid] + redq[2][tid] + redq[3][tid];
    float mean = S * (1.0f / HD2);
    float var = Q * (1.0f / HD2) - mean * mean;
    smean[tid] = mean;
    srstd[tid] = rsqrtf(var + LN_EPS);
  }
  __syncthreads();

#pragma unroll
  for (int rt = 0; rt < 2; ++rt)
#pragma unroll
    for (int c = 0; c < 4; ++c)
#pragma unroll
      for (int r = 0; r < 4; ++r) {
        int row = rt * 16 + (l >> 4) * 4 + r;
        int col = w * 64 + c * 16 + (l & 15);
        float t = (acc1[rt][c][r] - smean[row]) * srstd[row] * g1c[c] + e1c[c];
        Tl[row * PT + col] = f2bf(t);
      }
  __syncthreads();

  f4v acc2[2][2];
#pragma unroll
  for (int rt = 0; rt < 2; ++rt)
#pragma unroll
    for (int c = 0; c < 2; ++c) acc2[rt][c] = zz;

#pragma unroll
  for (int kt = 0; kt < 8; ++kt) {
    s8v a0 = *reinterpret_cast<const s8v*>(&Tl[(l & 15) * PT + kt * 32 + (l >> 4) * 8]);
    s8v a1 = *reinterpret_cast<const s8v*>(&Tl[((l & 15) + 16) * PT + kt * 32 + (l >> 4) * 8]);
#pragma unroll
    for (int c = 0; c < 2; ++c) {
      int ct2 = w * 2 + c;
      s8v bf = *reinterpret_cast<const s8v*>(&W2f[((size_t)(ct2 * 8 + kt) * 64 + l) * 8]);
      acc2[0][c] = __builtin_amdgcn_mfma_f32_16x16x32_bf16(a0, bf, acc2[0][c], 0, 0, 0);
      acc2[1][c] = __builtin_amdgcn_mfma_f32_16x16x32_bf16(a1, bf, acc2[1][c], 0, 0, 0);
    }
  }

#pragma unroll
  for (int rt = 0; rt < 2; ++rt)
#pragma unroll
    for (int r = 0; r < 4; ++r) {
      int row = row0 + rt * 16 + (l >> 4) * 4 + r;
      if (row < n) {
        float sc = os ? os[row] : 1.0f;
#pragma unroll
        for (int c = 0; c < 2; ++c)
          out[(size_t)row * HD + (w * 2 + c) * 16 + (l & 15)] = f2bf(acc2[rt][c][r] * sc);
      }
    }
}

// Per-node 3-key attention + LN. x1,x2 bf16; x3 f32 (in-place with out ok).
__global__ __launch_bounds__(256) void k_fuse(
    const float* __restrict__ emb, const unsigned short* __restrict__ x1,
    const unsigned short* __restrict__ x2, const float* __restrict__ x3,
    const float* __restrict__ g, const float* __restrict__ be,
    float* __restrict__ out, int n) {
  int tid = threadIdx.x;
  int row = blockIdx.x * 4 + (tid >> 6);
  if (row >= n) return;
  int l = tid & 63;
  size_t base = (size_t)row * 64 + l;
  float2 q = reinterpret_cast<const float2*>(emb)[base];
  ushort2 u1 = reinterpret_cast<const ushort2*>(x1)[base];
  ushort2 u2 = reinterpret_cast<const ushort2*>(x2)[base];
  float2 a = make_float2(bf2f(u1.x), bf2f(u1.y));
  float2 b = make_float2(bf2f(u2.x), bf2f(u2.y));
  float2 c = reinterpret_cast<const float2*>(x3)[base];
  float d1 = waveReduceSum(q.x * a.x + q.y * a.y);
  float d2 = waveReduceSum(q.x * b.x + q.y * b.y);
  float d3 = waveReduceSum(q.x * c.x + q.y * c.y);
  const float is = 0.088388347648318447f; // 1/sqrt(128)
  float s1 = d1 * is, s2 = d2 * is, s3 = d3 * is;
  float m = fmaxf(s1, fmaxf(s2, s3));
  float p1 = expf(s1 - m), p2 = expf(s2 - m), p3 = expf(s3 - m);
  float den = 1.0f / (p1 + p2 + p3);
  p1 *= den; p2 *= den; p3 *= den;
  float ox = p1 * a.x + p2 * b.x + p3 * c.x;
  float oy = p1 * a.y + p2 * b.y + p3 * c.y;
  float sum = waveReduceSum(ox + oy);
  float sq  = waveReduceSum(ox * ox + oy * oy);
  float mean = sum * (1.0f / HD);
  float var = sq * (1.0f / HD) - mean * mean;
  float rstd = rsqrtf(var + LN_EPS);
  float2 gg = reinterpret_cast<const float2*>(g)[l];
  float2 bb = reinterpret_cast<const float2*>(be)[l];
  float2 o;
  o.x = (ox - mean) * rstd * gg.x + bb.x;
  o.y = (oy - mean) * rstd * gg.y + bb.y;
  reinterpret_cast<float2*>(out)[base] = o;
}

extern "C" void kernel_launch(void* const* d_in, const int* in_sizes, int n_in,
                              void* d_out, int out_size, void* d_ws, size_t ws_size,
                              hipStream_t stream) {
  (void)n_in; (void)out_size; (void)ws_size;
  const float* emb  = (const float*)d_in[0];
  const int* e_soc  = (const int*)d_in[1];
  const int* e_dif  = (const int*)d_in[2];
  const int* e_hyp  = (const int*)d_in[3];
  const float* fuse_g = (const float*)d_in[4];
  const float* fuse_b = (const float*)d_in[5];
  const int N  = in_sizes[0] / HD;
  const int E1 = in_sizes[1] / 2;
  const int E2 = in_sizes[2] / 2;
  const int E3 = in_sizes[3] / 2;
  float* dout = (float*)d_out;

  // ---- workspace carve-up (~135 MB) ----
  char* wsb = (char*)d_ws;
  size_t o = 0;
  auto alloc = [&](size_t bytes) { void* p = wsb + o; o = (o + bytes + 15) & ~(size_t)15; return p; };
  int* deg_soc = (int*)alloc((size_t)4 * N * 4);
  int* deg_dif = deg_soc + N;
  int* deg_hn  = deg_soc + 2 * (size_t)N;
  int* deg_he  = deg_soc + 3 * (size_t)N;
  int* cur_soc = (int*)alloc((size_t)4 * N * 4);
  int* cur_dif = cur_soc + N;
  int* cur_hn  = cur_soc + 2 * (size_t)N;
  int* cur_he  = cur_soc + 3 * (size_t)N;
  int* off_soc = (int*)alloc((size_t)4 * N * 4);
  int* off_dif = off_soc + N;
  int* off_hn  = off_soc + 2 * (size_t)N;
  int* off_he  = off_soc + 3 * (size_t)N;
  int* bsum4  = (int*)alloc(4 * 1024 * 4);
  int* bbase4 = (int*)alloc(4 * 1024 * 4);
  int* col_soc = (int*)alloc((size_t)E1 * 4);
  int* col_dif = (int*)alloc((size_t)E2 * 4);
  int* col_hn  = (int*)alloc((size_t)E3 * 4);
  int* col_he  = (int*)alloc((size_t)E3 * 4);
  float* dsoc = (float*)alloc((size_t)N * 4);
  float* ddif = (float*)alloc((size_t)N * 4);
  float* Dinv = (float*)alloc((size_t)N * 4);
  float* Binv = (float*)alloc((size_t)N * 4);
  unsigned short* Wf1 = (unsigned short*)alloc((size_t)HD * HD2 * 2);
  unsigned short* Wf2 = (unsigned short*)alloc((size_t)HD2 * HD * 2);
  unsigned short* emb_bf = (unsigned short*)alloc((size_t)N * HD * 2);
  unsigned short* A_bf   = (unsigned short*)alloc((size_t)N * HD * 2);
  unsigned short* B_bf   = (unsigned short*)alloc((size_t)N * HD * 2);
  unsigned short* X1     = (unsigned short*)alloc((size_t)N * HD * 2);
  unsigned short* X2     = (unsigned short*)alloc((size_t)N * HD * 2);

  const int NB = (N + 255) / 256;
  int gN   = (N + 255) / 256;
  int gRow = (N + 3) / 4;
  int g16  = (N + 15) / 16;
  int gG   = (N + BM - 1) / BM;
  const int WF1_TOT = (HD2 / 16) * (HD / 32) * 64;   // 4096
  const int WF2_TOT = (HD / 16) * (HD2 / 32) * 64;   // 4096

  // ---- degrees ----
  k_izero<<<(4 * N + 255) / 256, 256, 0, stream>>>(deg_soc, 4 * N);
  k_icount<<<(E1 + 255) / 256, 256, 0, stream>>>(e_soc + E1, deg_soc, E1);
  k_icount<<<(E2 + 255) / 256, 256, 0, stream>>>(e_dif + E2, deg_dif, E2);
  k_icount<<<(E3 + 255) / 256, 256, 0, stream>>>(e_hyp,      deg_hn,  E3);
  k_icount<<<(E3 + 255) / 256, 256, 0, stream>>>(e_hyp + E3, deg_he,  E3);
  k_norms<<<gN, 256, 0, stream>>>(deg_soc, deg_dif, deg_hn, deg_he, dsoc, ddif, Dinv, Binv, N);

  // ---- CSR offsets + columns (4 graphs) ----
  const int* degs[4] = {deg_soc, deg_dif, deg_hn, deg_he};
  int* curs[4] = {cur_soc, cur_dif, cur_hn, cur_he};
  int* offs[4] = {off_soc, off_dif, off_hn, off_he};
  for (int g = 0; g < 4; ++g) {
    k_bsum<<<NB, 256, 0, stream>>>(degs[g], bsum4 + g * 1024, N);
    k_scanblk<<<1, 1024, 0, stream>>>(bsum4 + g * 1024, bbase4 + g * 1024, NB);
    k_fillof<<<NB, 256, 0, stream>>>(degs[g], bbase4 + g * 1024, offs[g], curs[g], N);
  }
  k_fillcol<<<(E1 + 255) / 256, 256, 0, stream>>>(e_soc,      e_soc + E1, cur_soc, col_soc, E1);
  k_fillcol<<<(E2 + 255) / 256, 256, 0, stream>>>(e_dif,      e_dif + E2, cur_dif, col_dif, E2);
  k_fillcol<<<(E3 + 255) / 256, 256, 0, stream>>>(e_hyp + E3, e_hyp,      cur_hn,  col_hn,  E3); // node -> hes
  k_fillcol<<<(E3 + 255) / 256, 256, 0, stream>>>(e_hyp,      e_hyp + E3, cur_he,  col_he,  E3); // he -> nodes

  // ---- emb -> bf16 once ----
  k_cvt<<<(N * HD / 4 + 255) / 256, 256, 0, stream>>>(emb, emb_bf, N * HD / 4);

  // ---- two GCN paths (soc -> X1, dif -> X2) ----
  for (int p = 0; p < 2; ++p) {
    float* dinv = (p == 0) ? dsoc : ddif;
    const int* off = offs[p];
    const int* end = curs[p];
    const int* col = (p == 0) ? col_soc : col_dif;
    unsigned short* Xp = (p == 0) ? X1 : X2;
    const float* W1  = (const float*)d_in[6 + p * 8 + 0];
    const float* b1  = (const float*)d_in[6 + p * 8 + 1];
    const float* g1  = (const float*)d_in[6 + p * 8 + 2];
    const float* be1 = (const float*)d_in[6 + p * 8 + 3];
    const float* W2  = (const float*)d_in[6 + p * 8 + 4];
    const float* b2  = (const float*)d_in[6 + p * 8 + 5];
    const float* g2  = (const float*)d_in[6 + p * 8 + 6];
    const float* be2 = (const float*)d_in[6 + p * 8 + 7];

    k_wfrag<<<(WF1_TOT + 255) / 256, 256, 0, stream>>>(W1, Wf1, HD / 32, HD2, WF1_TOT);
    k_wfrag<<<(WF2_TOT + 255) / 256, 256, 0, stream>>>(W2, Wf2, HD2 / 32, HD, WF2_TOT);

    // layer1 aggregation, all scales folded: A = dinv[d]*(Σ dinv[s]x[s] + dinv[d]x[d])
    k_gather4<0><<<g16, 256, 0, stream>>>(emb_bf, dinv, dinv, 2, dinv, off, end, col,
                                          nullptr, nullptr, nullptr, A_bf, N);
    k_fused_gemm_mfma<<<gG, 256, 0, stream>>>(A_bf, Wf1, b1, g1, be1, Wf2, dinv, B_bf, N);
    // layer2 aggregation + LN fused -> Xp (bf16)
    k_gather4<1><<<g16, 256, 0, stream>>>(B_bf, nullptr, nullptr, 1, dinv, off, end, col,
                                          b2, g2, be2, Xp, N);
  }

  // ---- HGNN path (hyp -> dout) ----
  {
    const float* W1  = (const float*)d_in[22 + 0];
    const float* b1  = (const float*)d_in[22 + 1];
    const float* g1  = (const float*)d_in[22 + 2];
    const float* be1 = (const float*)d_in[22 + 3];
    const float* W2  = (const float*)d_in[22 + 4];
    const float* b2  = (const float*)d_in[22 + 5];
    const float* g2  = (const float*)d_in[22 + 6];
    const float* be2 = (const float*)d_in[22 + 7];

    k_wfrag<<<(WF1_TOT + 255) / 256, 256, 0, stream>>>(W1, Wf1, HD / 32, HD2, WF1_TOT);
    k_wfrag<<<(WF2_TOT + 255) / 256, 256, 0, stream>>>(W2, Wf2, HD2 / 32, HD, WF2_TOT);

    // He = Binv * Σ_node emb ; Bv = Dinv * Σ_he He
    k_gather4<0><<<g16, 256, 0, stream>>>(emb_bf, nullptr, nullptr, 0, Binv, off_he, cur_he, col_he,
                                          nullptr, nullptr, nullptr, A_bf, N);
    k_gather4<0><<<g16, 256, 0, stream>>>(A_bf, nullptr, nullptr, 0, Dinv, off_hn, cur_hn, col_hn,
                                          nullptr, nullptr, nullptr, B_bf, N);
    k_fused_gemm_mfma<<<gG, 256, 0, stream>>>(B_bf, Wf1, b1, g1, be1, Wf2, nullptr, A_bf, N);
    k_gather4<0><<<g16, 256, 0, stream>>>(A_bf, nullptr, nullptr, 0, Binv, off_he, cur_he, col_he,
                                          nullptr, nullptr, nullptr, B_bf, N);
    // final node-aggregation + LN fused -> dout (f32)
    k_gather4<2><<<g16, 256, 0, stream>>>(B_bf, nullptr, nullptr, 0, Dinv, off_hn, cur_hn, col_hn,
                                          b2, g2, be2, dout, N);
  }

  // ---- fusion attention + LN -> d_out (in-place over X3) ----
  k_fuse<<<gRow, 256, 0, stream>>>(emb, X1, X2, dout, fuse_g, fuse_b, dout, N);
}